// Round 1
// baseline (3256.596 us; speedup 1.0000x reference)
//
#include <hip/hip_runtime.h>

#define NEG_SLOPE 0.2f
#define LN_EPS 1e-5f

// ---------------------------------------------------------------- prep kernels

__global__ void count_kernel(const int* __restrict__ dst0, const float* __restrict__ eattr,
                             int* __restrict__ cnt, float* __restrict__ easum, int E_) {
    int e = blockIdx.x * 256 + threadIdx.x;
    if (e >= E_) return;
    int d = dst0[e];
    atomicAdd(&cnt[d], 1);
    atomicAdd(&easum[d], eattr[e]);
}

__global__ void scan_kernel(const int* __restrict__ cnt, int* __restrict__ rowstart, int N_) {
    __shared__ int lds[1024];
    int t = threadIdx.x;
    int chunk = (N_ + 1023) >> 10;
    int begin = t * chunk;
    int end = begin + chunk; if (end > N_) end = N_; if (begin > N_) begin = N_;
    int s = 0;
    for (int i = begin; i < end; ++i) s += cnt[i] + 1;
    lds[t] = s;
    __syncthreads();
    for (int off = 1; off < 1024; off <<= 1) {
        int v = (t >= off) ? lds[t - off] : 0;
        __syncthreads();
        lds[t] += v;
        __syncthreads();
    }
    int run = lds[t] - s;  // exclusive base
    for (int i = begin; i < end; ++i) { rowstart[i] = run; run += cnt[i] + 1; }
    if (t == 1023) rowstart[N_] = lds[1023];
}

__global__ void selfloop_kernel(const int* __restrict__ cnt, const float* __restrict__ easum,
                                const int* __restrict__ rowstart, int* __restrict__ cursor,
                                int* __restrict__ csr_src, float* __restrict__ csr_ea, int N_) {
    int n = blockIdx.x * 256 + threadIdx.x;
    if (n >= N_) return;
    int rs = rowstart[n];
    csr_src[rs] = n;
    int c = cnt[n];
    csr_ea[rs] = easum[n] / (float)(c > 1 ? c : 1);
    cursor[n] = rs + 1;
}

__global__ void scatter_kernel(const int* __restrict__ src0, const int* __restrict__ dst0,
                               const float* __restrict__ eattr, int* __restrict__ cursor,
                               int* __restrict__ csr_src, float* __restrict__ csr_ea, int E_) {
    int e = blockIdx.x * 256 + threadIdx.x;
    if (e >= E_) return;
    int d = dst0[e];
    int p = atomicAdd(&cursor[d], 1);
    csr_src[p] = src0[e];
    csr_ea[p] = eattr[e];
}

// transpose Wl/Wr (3 each, 128x128) into Wt[6][j][k] = W[k][j]
__global__ void wtrans_kernel(const float* __restrict__ Wl, const float* __restrict__ Wr,
                              float* __restrict__ Wt) {
    int idx = blockIdx.x * 256 + threadIdx.x;
    if (idx >= 6 * 16384) return;
    int m = idx >> 14;
    int j = (idx >> 7) & 127;
    int k = idx & 127;
    const float* W = (m < 3) ? (Wl + m * 16384) : (Wr + (m - 3) * 16384);
    Wt[idx] = W[k * 128 + j];
}

// ---------------------------------------------------------------- input proj

__global__ void in_proj_kernel(const float* __restrict__ x, const float* __restrict__ W_in,
                               const float* __restrict__ b_in, float* __restrict__ h, int N_) {
    int idx = blockIdx.x * 256 + threadIdx.x;
    int n = idx >> 7, j = idx & 127;
    if (n >= N_) return;
    float acc = b_in[j];
    const float* xrow = x + n * 32;
#pragma unroll
    for (int k = 0; k < 32; ++k) acc += xrow[k] * W_in[k * 128 + j];
    h[n * 128 + j] = acc;
}

// ---------------------------------------------------------------- xl/xr GEMM
// block = 256 (4 waves), 64 rows/block, wave handles 16 rows; lane = cols (j, j+64)
// for both Wl and Wr. h tile staged in LDS; W read transposed via float4.

__global__ __launch_bounds__(256, 4) void proj_kernel(
    const float* __restrict__ h, const float* __restrict__ Wlt, const float* __restrict__ Wrt,
    const float* __restrict__ bl, const float* __restrict__ br,
    float* __restrict__ xl, float* __restrict__ xr, int N_) {
    __shared__ float hs[64 * 128];
    int t = threadIdx.x;
    int row0 = blockIdx.x * 64;
    {
        const float4* src = (const float4*)(h + (size_t)row0 * 128);
        float4* dst = (float4*)hs;
        int maxv = (N_ - row0) * 32;  // valid float4 count
#pragma unroll
        for (int i = 0; i < 8; ++i) {
            int o = i * 256 + t;
            int oc = o < maxv ? o : 0;
            dst[o] = src[oc];
        }
    }
    __syncthreads();
    int wave = t >> 6, lane = t & 63;
    int rbase = wave * 16;
    const float* wl0 = Wlt + lane * 128;
    const float* wl1 = Wlt + (lane + 64) * 128;
    const float* wr0 = Wrt + lane * 128;
    const float* wr1 = Wrt + (lane + 64) * 128;
    float accl0[16], accl1[16], accr0[16], accr1[16];
    float bL0 = bl[lane], bL1 = bl[lane + 64], bR0 = br[lane], bR1 = br[lane + 64];
#pragma unroll
    for (int r = 0; r < 16; ++r) { accl0[r] = bL0; accl1[r] = bL1; accr0[r] = bR0; accr1[r] = bR1; }
    for (int k = 0; k < 128; k += 4) {
        float4 a = *(const float4*)(wl0 + k);
        float4 b = *(const float4*)(wl1 + k);
        float4 c = *(const float4*)(wr0 + k);
        float4 d = *(const float4*)(wr1 + k);
#pragma unroll
        for (int r = 0; r < 16; ++r) {
            float4 hv = *(const float4*)(&hs[(rbase + r) * 128 + k]);
            accl0[r] += hv.x * a.x + hv.y * a.y + hv.z * a.z + hv.w * a.w;
            accl1[r] += hv.x * b.x + hv.y * b.y + hv.z * b.z + hv.w * b.w;
            accr0[r] += hv.x * c.x + hv.y * c.y + hv.z * c.z + hv.w * c.w;
            accr1[r] += hv.x * d.x + hv.y * d.y + hv.z * d.z + hv.w * d.w;
        }
    }
#pragma unroll
    for (int r = 0; r < 16; ++r) {
        int row = row0 + rbase + r;
        if (row < N_) {
            xl[row * 128 + lane] = accl0[r];
            xl[row * 128 + lane + 64] = accl1[r];
            xr[row * 128 + lane] = accr0[r];
            xr[row * 128 + lane + 64] = accr1[r];
        }
    }
}

// ---------------------------------------------------------------- per-node aggregation
// one wave per node; lane = channels (2l, 2l+1); head = lane/16.
// online softmax over CSR edge list; fused bias+ELU+residual+LayerNorm; h in-place.

__global__ __launch_bounds__(256) void aggregate_kernel(
    float* __restrict__ h, const float* __restrict__ xl, const float* __restrict__ xr,
    const int* __restrict__ rowstart, const int* __restrict__ csr_src,
    const float* __restrict__ csr_ea, const float* __restrict__ We,
    const float* __restrict__ att, const float* __restrict__ bc,
    const float* __restrict__ ln_g, const float* __restrict__ ln_b, int N_) {
    int wave = threadIdx.x >> 6, lane = threadIdx.x & 63;
    int n = blockIdx.x * 4 + wave;
    if (n >= N_) return;
    int c0 = lane * 2;
    int head = lane >> 4;
    float2 xr2 = *(const float2*)(xr + (size_t)n * 128 + c0);
    float2 we2 = *(const float2*)(We + c0);
    float2 at2 = *(const float2*)(att + head * 32 + (c0 & 31));
    int rs = rowstart[n], re = rowstart[n + 1];
    float m_run = -3.0e38f, d_run = 0.f;
    float accx = 0.f, accy = 0.f;
    for (int p = rs; p < re; ++p) {
        int s = csr_src[p];
        float eav = csr_ea[p];
        float2 xls = *(const float2*)(xl + (size_t)s * 128 + c0);
        float mx = xls.x + xr2.x + eav * we2.x;
        float my = xls.y + xr2.y + eav * we2.y;
        mx = mx > 0.f ? mx : NEG_SLOPE * mx;
        my = my > 0.f ? my : NEG_SLOPE * my;
        float part = mx * at2.x + my * at2.y;
        part += __shfl_xor(part, 1);
        part += __shfl_xor(part, 2);
        part += __shfl_xor(part, 4);
        part += __shfl_xor(part, 8);  // alpha for this head, all 16 lanes
        float nm = fmaxf(m_run, part);
        float sc = __expf(m_run - nm);
        float pe = __expf(part - nm);
        d_run = d_run * sc + pe;
        accx = accx * sc + pe * xls.x;
        accy = accy * sc + pe * xls.y;
        m_run = nm;
    }
    float inv = 1.f / d_run;
    float2 bc2 = *(const float2*)(bc + c0);
    float ox = accx * inv + bc2.x;
    float oy = accy * inv + bc2.y;
    ox = ox > 0.f ? ox : (__expf(ox) - 1.f);  // elu
    oy = oy > 0.f ? oy : (__expf(oy) - 1.f);
    float2 h2 = *(const float2*)(h + (size_t)n * 128 + c0);
    float tx = h2.x + ox, ty = h2.y + oy;
    float sum = tx + ty;
#pragma unroll
    for (int m = 1; m < 64; m <<= 1) sum += __shfl_xor(sum, m);
    float mu = sum * (1.f / 128.f);
    float dx = tx - mu, dy = ty - mu;
    float vs = dx * dx + dy * dy;
#pragma unroll
    for (int m = 1; m < 64; m <<= 1) vs += __shfl_xor(vs, m);
    float rstd = rsqrtf(vs * (1.f / 128.f) + LN_EPS);
    float2 g2 = *(const float2*)(ln_g + c0);
    float2 b2 = *(const float2*)(ln_b + c0);
    float2 hn;
    hn.x = dx * rstd * g2.x + b2.x;
    hn.y = dy * rstd * g2.y + b2.y;
    *(float2*)(h + (size_t)n * 128 + c0) = hn;
}

// ---------------------------------------------------------------- outputs

__global__ __launch_bounds__(256) void final_kernel(
    const float* __restrict__ h, const float* __restrict__ Wn, const float* __restrict__ bn,
    const int* __restrict__ batch, float* __restrict__ node_emb, float* __restrict__ h_out,
    float* __restrict__ gsum, float* __restrict__ gcnt, int N_) {
    int wave = threadIdx.x >> 6, lane = threadIdx.x & 63;
    int n = blockIdx.x * 4 + wave;
    if (n >= N_) return;
    float2 h2 = *(const float2*)(h + (size_t)n * 128 + lane * 2);
    *(float2*)(h_out + (size_t)n * 128 + lane * 2) = h2;
    int b = batch[n];
    atomicAdd(&gsum[b * 128 + lane * 2], h2.x);
    atomicAdd(&gsum[b * 128 + lane * 2 + 1], h2.y);
    if (lane == 0) atomicAdd(gcnt + b, 1.0f);
    float acc = bn[lane];
#pragma unroll 8
    for (int k2 = 0; k2 < 64; ++k2) {
        float hx = __shfl(h2.x, k2);
        float hy = __shfl(h2.y, k2);
        acc += hx * Wn[(2 * k2) * 64 + lane] + hy * Wn[(2 * k2 + 1) * 64 + lane];
    }
    node_emb[(size_t)n * 64 + lane] = acc;
}

__global__ void graph_kernel(const float* __restrict__ gsum, const float* __restrict__ gcnt,
                             const float* __restrict__ Wg1, const float* __restrict__ bg1,
                             const float* __restrict__ Wg2, const float* __restrict__ bg2,
                             float* __restrict__ graph_emb) {
    __shared__ float gm[8 * 128];
    __shared__ float t1[8 * 128];
    int t = threadIdx.x;
    for (int i = t; i < 1024; i += 256) {
        int b = i >> 7;
        float c = gcnt[b];
        c = c > 1.f ? c : 1.f;
        gm[i] = gsum[i] / c;
    }
    __syncthreads();
    for (int i = t; i < 1024; i += 256) {
        int r = i >> 7, j = i & 127;
        float acc = bg1[j];
        for (int k = 0; k < 128; ++k) acc += gm[r * 128 + k] * Wg1[k * 128 + j];
        t1[i] = acc > 0.f ? acc : (__expf(acc) - 1.f);
    }
    __syncthreads();
    for (int i = t; i < 512; i += 256) {
        int r = i >> 6, j = i & 63;
        float acc = bg2[j];
        for (int k = 0; k < 128; ++k) acc += t1[r * 128 + k] * Wg2[k * 64 + j];
        graph_emb[r * 64 + j] = acc;
    }
}

// ---------------------------------------------------------------- launch

extern "C" void kernel_launch(void* const* d_in, const int* in_sizes, int n_in,
                              void* d_out, int out_size, void* d_ws, size_t ws_size,
                              hipStream_t stream) {
    const float* x         = (const float*)d_in[0];
    const int*   edge_index= (const int*)d_in[1];
    const float* edge_attr = (const float*)d_in[2];
    const int*   batch     = (const int*)d_in[3];
    const float* W_in      = (const float*)d_in[4];
    const float* b_in      = (const float*)d_in[5];
    const float* Wl        = (const float*)d_in[6];
    const float* bl        = (const float*)d_in[7];
    const float* Wr        = (const float*)d_in[8];
    const float* br        = (const float*)d_in[9];
    const float* We        = (const float*)d_in[10];
    const float* att       = (const float*)d_in[11];
    const float* bc        = (const float*)d_in[12];
    const float* ln_g      = (const float*)d_in[13];
    const float* ln_b      = (const float*)d_in[14];
    const float* Wn        = (const float*)d_in[15];
    const float* bn        = (const float*)d_in[16];
    const float* Wg1       = (const float*)d_in[17];
    const float* bg1       = (const float*)d_in[18];
    const float* Wg2       = (const float*)d_in[19];
    const float* bg2       = (const float*)d_in[20];

    const int N_ = in_sizes[3];   // batch is (N,)
    const int E_ = in_sizes[2];   // edge_attr is (E,1)

    const int* src0 = edge_index;
    const int* dst0 = edge_index + E_;

    float* ws = (float*)d_ws;
    float* h      = ws;                              // N*128
    float* xl     = h + (size_t)N_ * 128;            // N*128
    float* xr     = xl + (size_t)N_ * 128;           // N*128
    float* csr_ea = xr + (size_t)N_ * 128;           // E+N
    float* Wt     = csr_ea + (size_t)(E_ + N_);      // 6*16384
    float* gsum   = Wt + 6 * 16384;                  // 1024
    float* gcnt   = gsum + 1024;                     // 16 (8 used)
    float* easum  = gcnt + 16;                       // N
    int* cnt      = (int*)(easum + N_);              // N
    int* rowstart = cnt + N_;                        // N+1
    int* cursor   = rowstart + N_ + 1;               // N
    int* csr_src  = cursor + N_;                     // E+N

    float* out_f     = (float*)d_out;
    float* node_emb  = out_f;                               // N*64
    float* graph_emb = out_f + (size_t)N_ * 64;             // 8*64
    float* h_out     = out_f + (size_t)N_ * 64 + 8 * 64;    // N*128

    hipMemsetAsync(cnt, 0, N_ * sizeof(int), stream);
    hipMemsetAsync(easum, 0, N_ * sizeof(float), stream);
    hipMemsetAsync(gsum, 0, (1024 + 16) * sizeof(float), stream);

    wtrans_kernel<<<(6 * 16384 + 255) / 256, 256, 0, stream>>>(Wl, Wr, Wt);
    count_kernel<<<(E_ + 255) / 256, 256, 0, stream>>>(dst0, edge_attr, cnt, easum, E_);
    scan_kernel<<<1, 1024, 0, stream>>>(cnt, rowstart, N_);
    selfloop_kernel<<<(N_ + 255) / 256, 256, 0, stream>>>(cnt, easum, rowstart, cursor,
                                                          csr_src, csr_ea, N_);
    scatter_kernel<<<(E_ + 255) / 256, 256, 0, stream>>>(src0, dst0, edge_attr, cursor,
                                                         csr_src, csr_ea, E_);
    in_proj_kernel<<<((N_ * 128) + 255) / 256, 256, 0, stream>>>(x, W_in, b_in, h, N_);

    for (int l = 0; l < 3; ++l) {
        proj_kernel<<<(N_ + 63) / 64, 256, 0, stream>>>(
            h, Wt + l * 16384, Wt + (3 + l) * 16384, bl + l * 128, br + l * 128, xl, xr, N_);
        aggregate_kernel<<<(N_ + 3) / 4, 256, 0, stream>>>(
            h, xl, xr, rowstart, csr_src, csr_ea, We + l * 128, att + l * 128,
            bc + l * 128, ln_g + l * 128, ln_b + l * 128, N_);
    }

    final_kernel<<<(N_ + 3) / 4, 256, 0, stream>>>(h, Wn, bn, batch, node_emb, h_out,
                                                   gsum, gcnt, N_);
    graph_kernel<<<1, 256, 0, stream>>>(gsum, gcnt, Wg1, bg1, Wg2, bg2, graph_emb);
}

// Round 2
// 2522.839 us; speedup vs baseline: 1.2908x; 1.2908x over previous
//
#include <hip/hip_runtime.h>

#define NEG_SLOPE 0.2f
#define LN_EPS 1e-5f

// ---------------------------------------------------------------- prep kernels

__global__ void count_kernel(const int* __restrict__ dst0, const float* __restrict__ eattr,
                             int* __restrict__ cnt, float* __restrict__ easum, int E_) {
    int e = blockIdx.x * 256 + threadIdx.x;
    if (e >= E_) return;
    int d = dst0[e];
    atomicAdd(&cnt[d], 1);
    atomicAdd(&easum[d], eattr[e]);
}

__global__ void scan_kernel(const int* __restrict__ cnt, int* __restrict__ rowstart, int N_) {
    __shared__ int lds[1024];
    int t = threadIdx.x;
    int chunk = (N_ + 1023) >> 10;
    int begin = t * chunk;
    int end = begin + chunk; if (end > N_) end = N_; if (begin > N_) begin = N_;
    int s = 0;
    for (int i = begin; i < end; ++i) s += cnt[i] + 1;
    lds[t] = s;
    __syncthreads();
    for (int off = 1; off < 1024; off <<= 1) {
        int v = (t >= off) ? lds[t - off] : 0;
        __syncthreads();
        lds[t] += v;
        __syncthreads();
    }
    int run = lds[t] - s;  // exclusive base
    for (int i = begin; i < end; ++i) { rowstart[i] = run; run += cnt[i] + 1; }
    if (t == 1023) rowstart[N_] = lds[1023];
}

__global__ void selfloop_kernel(const int* __restrict__ cnt, const float* __restrict__ easum,
                                const int* __restrict__ rowstart, int* __restrict__ cursor,
                                int* __restrict__ csr_src, float* __restrict__ csr_ea, int N_) {
    int n = blockIdx.x * 256 + threadIdx.x;
    if (n >= N_) return;
    int rs = rowstart[n];
    csr_src[rs] = n;
    int c = cnt[n];
    csr_ea[rs] = easum[n] / (float)(c > 1 ? c : 1);
    cursor[n] = rs + 1;
}

__global__ void scatter_kernel(const int* __restrict__ src0, const int* __restrict__ dst0,
                               const float* __restrict__ eattr, int* __restrict__ cursor,
                               int* __restrict__ csr_src, float* __restrict__ csr_ea, int E_) {
    int e = blockIdx.x * 256 + threadIdx.x;
    if (e >= E_) return;
    int d = dst0[e];
    int p = atomicAdd(&cursor[d], 1);
    csr_src[p] = src0[e];
    csr_ea[p] = eattr[e];
}

// transpose Wl/Wr (3 each, 128x128) into Wt[6][j][k] = W[k][j]
__global__ void wtrans_kernel(const float* __restrict__ Wl, const float* __restrict__ Wr,
                              float* __restrict__ Wt) {
    int idx = blockIdx.x * 256 + threadIdx.x;
    if (idx >= 6 * 16384) return;
    int m = idx >> 14;
    int j = (idx >> 7) & 127;
    int k = idx & 127;
    const float* W = (m < 3) ? (Wl + m * 16384) : (Wr + (m - 3) * 16384);
    Wt[idx] = W[k * 128 + j];
}

// ---------------------------------------------------------------- input proj

__global__ void in_proj_kernel(const float* __restrict__ x, const float* __restrict__ W_in,
                               const float* __restrict__ b_in, float* __restrict__ h, int N_) {
    int idx = blockIdx.x * 256 + threadIdx.x;
    int n = idx >> 7, j = idx & 127;
    if (n >= N_) return;
    float acc = b_in[j];
    const float* xrow = x + n * 32;
#pragma unroll
    for (int k = 0; k < 32; ++k) acc += xrow[k] * W_in[k * 128 + j];
    h[n * 128 + j] = acc;
}

// ---------------------------------------------------------------- xl/xr GEMM

__global__ __launch_bounds__(256, 4) void proj_kernel(
    const float* __restrict__ h, const float* __restrict__ Wlt, const float* __restrict__ Wrt,
    const float* __restrict__ bl, const float* __restrict__ br,
    float* __restrict__ xl, float* __restrict__ xr, int N_) {
    __shared__ float hs[64 * 128];
    int t = threadIdx.x;
    int row0 = blockIdx.x * 64;
    {
        const float4* src = (const float4*)(h + (size_t)row0 * 128);
        float4* dst = (float4*)hs;
        int maxv = (N_ - row0) * 32;  // valid float4 count
#pragma unroll
        for (int i = 0; i < 8; ++i) {
            int o = i * 256 + t;
            int oc = o < maxv ? o : 0;
            dst[o] = src[oc];
        }
    }
    __syncthreads();
    int wave = t >> 6, lane = t & 63;
    int rbase = wave * 16;
    const float* wl0 = Wlt + lane * 128;
    const float* wl1 = Wlt + (lane + 64) * 128;
    const float* wr0 = Wrt + lane * 128;
    const float* wr1 = Wrt + (lane + 64) * 128;
    float accl0[16], accl1[16], accr0[16], accr1[16];
    float bL0 = bl[lane], bL1 = bl[lane + 64], bR0 = br[lane], bR1 = br[lane + 64];
#pragma unroll
    for (int r = 0; r < 16; ++r) { accl0[r] = bL0; accl1[r] = bL1; accr0[r] = bR0; accr1[r] = bR1; }
    for (int k = 0; k < 128; k += 4) {
        float4 a = *(const float4*)(wl0 + k);
        float4 b = *(const float4*)(wl1 + k);
        float4 c = *(const float4*)(wr0 + k);
        float4 d = *(const float4*)(wr1 + k);
#pragma unroll
        for (int r = 0; r < 16; ++r) {
            float4 hv = *(const float4*)(&hs[(rbase + r) * 128 + k]);
            accl0[r] += hv.x * a.x + hv.y * a.y + hv.z * a.z + hv.w * a.w;
            accl1[r] += hv.x * b.x + hv.y * b.y + hv.z * b.z + hv.w * b.w;
            accr0[r] += hv.x * c.x + hv.y * c.y + hv.z * c.z + hv.w * c.w;
            accr1[r] += hv.x * d.x + hv.y * d.y + hv.z * d.z + hv.w * d.w;
        }
    }
#pragma unroll
    for (int r = 0; r < 16; ++r) {
        int row = row0 + rbase + r;
        if (row < N_) {
            xl[row * 128 + lane] = accl0[r];
            xl[row * 128 + lane + 64] = accl1[r];
            xr[row * 128 + lane] = accr0[r];
            xr[row * 128 + lane + 64] = accr1[r];
        }
    }
}

// ---------------------------------------------------------------- per-node aggregation

__global__ __launch_bounds__(256) void aggregate_kernel(
    float* __restrict__ h, const float* __restrict__ xl, const float* __restrict__ xr,
    const int* __restrict__ rowstart, const int* __restrict__ csr_src,
    const float* __restrict__ csr_ea, const float* __restrict__ We,
    const float* __restrict__ att, const float* __restrict__ bc,
    const float* __restrict__ ln_g, const float* __restrict__ ln_b, int N_) {
    int wave = threadIdx.x >> 6, lane = threadIdx.x & 63;
    int n = blockIdx.x * 4 + wave;
    if (n >= N_) return;
    int c0 = lane * 2;
    int head = lane >> 4;
    float2 xr2 = *(const float2*)(xr + (size_t)n * 128 + c0);
    float2 we2 = *(const float2*)(We + c0);
    float2 at2 = *(const float2*)(att + head * 32 + (c0 & 31));
    int rs = rowstart[n], re = rowstart[n + 1];
    float m_run = -3.0e38f, d_run = 0.f;
    float accx = 0.f, accy = 0.f;
    for (int p = rs; p < re; ++p) {
        int s = csr_src[p];
        float eav = csr_ea[p];
        float2 xls = *(const float2*)(xl + (size_t)s * 128 + c0);
        float mx = xls.x + xr2.x + eav * we2.x;
        float my = xls.y + xr2.y + eav * we2.y;
        mx = mx > 0.f ? mx : NEG_SLOPE * mx;
        my = my > 0.f ? my : NEG_SLOPE * my;
        float part = mx * at2.x + my * at2.y;
        part += __shfl_xor(part, 1);
        part += __shfl_xor(part, 2);
        part += __shfl_xor(part, 4);
        part += __shfl_xor(part, 8);  // alpha for this head, all 16 lanes
        float nm = fmaxf(m_run, part);
        float sc = __expf(m_run - nm);
        float pe = __expf(part - nm);
        d_run = d_run * sc + pe;
        accx = accx * sc + pe * xls.x;
        accy = accy * sc + pe * xls.y;
        m_run = nm;
    }
    float inv = 1.f / d_run;
    float2 bc2 = *(const float2*)(bc + c0);
    float ox = accx * inv + bc2.x;
    float oy = accy * inv + bc2.y;
    ox = ox > 0.f ? ox : (__expf(ox) - 1.f);  // elu
    oy = oy > 0.f ? oy : (__expf(oy) - 1.f);
    float2 h2 = *(const float2*)(h + (size_t)n * 128 + c0);
    float tx = h2.x + ox, ty = h2.y + oy;
    float sum = tx + ty;
#pragma unroll
    for (int m = 1; m < 64; m <<= 1) sum += __shfl_xor(sum, m);
    float mu = sum * (1.f / 128.f);
    float dx = tx - mu, dy = ty - mu;
    float vs = dx * dx + dy * dy;
#pragma unroll
    for (int m = 1; m < 64; m <<= 1) vs += __shfl_xor(vs, m);
    float rstd = rsqrtf(vs * (1.f / 128.f) + LN_EPS);
    float2 g2 = *(const float2*)(ln_g + c0);
    float2 b2 = *(const float2*)(ln_b + c0);
    float2 hn;
    hn.x = dx * rstd * g2.x + b2.x;
    hn.y = dy * rstd * g2.y + b2.y;
    *(float2*)(h + (size_t)n * 128 + c0) = hn;
}

// ---------------------------------------------------------------- outputs
// wave = contiguous chunk of nodes; lane = 2 channels. gsum accumulated in
// registers per batch-run (batch is sorted) -> ~1 flush of 128 atomics per wave.

__global__ __launch_bounds__(256) void final_kernel(
    const float* __restrict__ h, const float* __restrict__ Wn, const float* __restrict__ bn,
    const int* __restrict__ batch, float* __restrict__ node_emb, float* __restrict__ h_out,
    float* __restrict__ gsum, float* __restrict__ gcnt, int N_, int chunk) {
    int wave_id = (blockIdx.x * 256 + threadIdx.x) >> 6;
    int lane = threadIdx.x & 63;
    int w0 = wave_id * chunk;
    if (w0 >= N_) return;
    int w1 = w0 + chunk; if (w1 > N_) w1 = N_;
    int c0 = lane * 2;
    float bnv = bn[lane];
    int cur_b = batch[w0];
    float accx = 0.f, accy = 0.f, cntf = 0.f;
    for (int n = w0; n < w1; ++n) {
        float2 h2 = *(const float2*)(h + (size_t)n * 128 + c0);
        *(float2*)(h_out + (size_t)n * 128 + c0) = h2;
        int b = batch[n];
        if (b != cur_b) {
            atomicAdd(&gsum[cur_b * 128 + c0], accx);
            atomicAdd(&gsum[cur_b * 128 + c0 + 1], accy);
            if (lane == 0) atomicAdd(gcnt + cur_b, cntf);
            accx = accy = cntf = 0.f;
            cur_b = b;
        }
        accx += h2.x; accy += h2.y; cntf += 1.f;
        float acc = bnv;
#pragma unroll 16
        for (int k2 = 0; k2 < 64; ++k2) {
            float hx = __shfl(h2.x, k2);
            float hy = __shfl(h2.y, k2);
            acc += hx * Wn[(2 * k2) * 64 + lane] + hy * Wn[(2 * k2 + 1) * 64 + lane];
        }
        node_emb[(size_t)n * 64 + lane] = acc;
    }
    atomicAdd(&gsum[cur_b * 128 + c0], accx);
    atomicAdd(&gsum[cur_b * 128 + c0 + 1], accy);
    if (lane == 0) atomicAdd(gcnt + cur_b, cntf);
}

__global__ void graph_kernel(const float* __restrict__ gsum, const float* __restrict__ gcnt,
                             const float* __restrict__ Wg1, const float* __restrict__ bg1,
                             const float* __restrict__ Wg2, const float* __restrict__ bg2,
                             float* __restrict__ graph_emb) {
    __shared__ float gm[8 * 128];
    __shared__ float t1[8 * 128];
    int t = threadIdx.x;
    for (int i = t; i < 1024; i += 256) {
        int b = i >> 7;
        float c = gcnt[b];
        c = c > 1.f ? c : 1.f;
        gm[i] = gsum[i] / c;
    }
    __syncthreads();
    for (int i = t; i < 1024; i += 256) {
        int r = i >> 7, j = i & 127;
        float acc = bg1[j];
        for (int k = 0; k < 128; ++k) acc += gm[r * 128 + k] * Wg1[k * 128 + j];
        t1[i] = acc > 0.f ? acc : (__expf(acc) - 1.f);
    }
    __syncthreads();
    for (int i = t; i < 512; i += 256) {
        int r = i >> 6, j = i & 63;
        float acc = bg2[j];
        for (int k = 0; k < 128; ++k) acc += t1[r * 128 + k] * Wg2[k * 64 + j];
        graph_emb[r * 64 + j] = acc;
    }
}

// ---------------------------------------------------------------- launch

extern "C" void kernel_launch(void* const* d_in, const int* in_sizes, int n_in,
                              void* d_out, int out_size, void* d_ws, size_t ws_size,
                              hipStream_t stream) {
    const float* x         = (const float*)d_in[0];
    const int*   edge_index= (const int*)d_in[1];
    const float* edge_attr = (const float*)d_in[2];
    const int*   batch     = (const int*)d_in[3];
    const float* W_in      = (const float*)d_in[4];
    const float* b_in      = (const float*)d_in[5];
    const float* Wl        = (const float*)d_in[6];
    const float* bl        = (const float*)d_in[7];
    const float* Wr        = (const float*)d_in[8];
    const float* br        = (const float*)d_in[9];
    const float* We        = (const float*)d_in[10];
    const float* att       = (const float*)d_in[11];
    const float* bc        = (const float*)d_in[12];
    const float* ln_g      = (const float*)d_in[13];
    const float* ln_b      = (const float*)d_in[14];
    const float* Wn        = (const float*)d_in[15];
    const float* bn        = (const float*)d_in[16];
    const float* Wg1       = (const float*)d_in[17];
    const float* bg1       = (const float*)d_in[18];
    const float* Wg2       = (const float*)d_in[19];
    const float* bg2       = (const float*)d_in[20];

    const int N_ = in_sizes[3];   // batch is (N,)
    const int E_ = in_sizes[2];   // edge_attr is (E,1)

    const int* src0 = edge_index;
    const int* dst0 = edge_index + E_;

    float* ws = (float*)d_ws;
    float* h      = ws;                              // N*128
    float* xl     = h + (size_t)N_ * 128;            // N*128
    float* xr     = xl + (size_t)N_ * 128;           // N*128
    float* csr_ea = xr + (size_t)N_ * 128;           // E+N
    float* Wt     = csr_ea + (size_t)(E_ + N_);      // 6*16384
    float* gsum   = Wt + 6 * 16384;                  // 1024
    float* gcnt   = gsum + 1024;                     // 16 (8 used)
    float* easum  = gcnt + 16;                       // N
    int* cnt      = (int*)(easum + N_);              // N
    int* rowstart = cnt + N_;                        // N+1
    int* cursor   = rowstart + N_ + 1;               // N
    int* csr_src  = cursor + N_;                     // E+N

    float* out_f     = (float*)d_out;
    float* node_emb  = out_f;                               // N*64
    float* graph_emb = out_f + (size_t)N_ * 64;             // 8*64
    float* h_out     = out_f + (size_t)N_ * 64 + 8 * 64;    // N*128

    hipMemsetAsync(cnt, 0, N_ * sizeof(int), stream);
    hipMemsetAsync(easum, 0, N_ * sizeof(float), stream);
    hipMemsetAsync(gsum, 0, (1024 + 16) * sizeof(float), stream);

    wtrans_kernel<<<(6 * 16384 + 255) / 256, 256, 0, stream>>>(Wl, Wr, Wt);
    count_kernel<<<(E_ + 255) / 256, 256, 0, stream>>>(dst0, edge_attr, cnt, easum, E_);
    scan_kernel<<<1, 1024, 0, stream>>>(cnt, rowstart, N_);
    selfloop_kernel<<<(N_ + 255) / 256, 256, 0, stream>>>(cnt, easum, rowstart, cursor,
                                                          csr_src, csr_ea, N_);
    scatter_kernel<<<(E_ + 255) / 256, 256, 0, stream>>>(src0, dst0, edge_attr, cursor,
                                                         csr_src, csr_ea, E_);
    in_proj_kernel<<<((N_ * 128) + 255) / 256, 256, 0, stream>>>(x, W_in, b_in, h, N_);

    for (int l = 0; l < 3; ++l) {
        proj_kernel<<<(N_ + 63) / 64, 256, 0, stream>>>(
            h, Wt + l * 16384, Wt + (3 + l) * 16384, bl + l * 128, br + l * 128, xl, xr, N_);
        aggregate_kernel<<<(N_ + 3) / 4, 256, 0, stream>>>(
            h, xl, xr, rowstart, csr_src, csr_ea, We + l * 128, att + l * 128,
            bc + l * 128, ln_g + l * 128, ln_b + l * 128, N_);
    }

    // 2048 waves, each a contiguous node chunk (batch sorted -> ~1 gsum flush/wave)
    {
        int total_waves = 2048;
        int chunk = (N_ + total_waves - 1) / total_waves;
        final_kernel<<<total_waves / 4, 256, 0, stream>>>(h, Wn, bn, batch, node_emb, h_out,
                                                          gsum, gcnt, N_, chunk);
    }
    graph_kernel<<<1, 256, 0, stream>>>(gsum, gcnt, Wg1, bg1, Wg2, bg2, graph_emb);
}

// Round 3
// 1092.201 us; speedup vs baseline: 2.9817x; 2.3099x over previous
//
#include <hip/hip_runtime.h>

#define NEG_SLOPE 0.2f
#define LN_EPS 1e-5f

// ---------------------------------------------------------------- prep kernels

__global__ void count_kernel(const int* __restrict__ dst0, const float* __restrict__ eattr,
                             int* __restrict__ cnt, float* __restrict__ easum, int E_) {
    int e = blockIdx.x * 256 + threadIdx.x;
    if (e >= E_) return;
    int d = dst0[e];
    atomicAdd(&cnt[d], 1);
    atomicAdd(&easum[d], eattr[e]);
}

__global__ void scan_kernel(const int* __restrict__ cnt, int* __restrict__ rowstart, int N_) {
    __shared__ int lds[1024];
    int t = threadIdx.x;
    int chunk = (N_ + 1023) >> 10;
    int begin = t * chunk;
    int end = begin + chunk; if (end > N_) end = N_; if (begin > N_) begin = N_;
    int s = 0;
    for (int i = begin; i < end; ++i) s += cnt[i] + 1;
    lds[t] = s;
    __syncthreads();
    for (int off = 1; off < 1024; off <<= 1) {
        int v = (t >= off) ? lds[t - off] : 0;
        __syncthreads();
        lds[t] += v;
        __syncthreads();
    }
    int run = lds[t] - s;  // exclusive base
    for (int i = begin; i < end; ++i) { rowstart[i] = run; run += cnt[i] + 1; }
    if (t == 1023) rowstart[N_] = lds[1023];
}

__global__ void selfloop_kernel(const int* __restrict__ cnt, const float* __restrict__ easum,
                                const int* __restrict__ rowstart, int* __restrict__ cursor,
                                int* __restrict__ csr_src, float* __restrict__ csr_ea, int N_) {
    int n = blockIdx.x * 256 + threadIdx.x;
    if (n >= N_) return;
    int rs = rowstart[n];
    csr_src[rs] = n;
    int c = cnt[n];
    csr_ea[rs] = easum[n] / (float)(c > 1 ? c : 1);
    cursor[n] = rs + 1;
}

__global__ void scatter_kernel(const int* __restrict__ src0, const int* __restrict__ dst0,
                               const float* __restrict__ eattr, int* __restrict__ cursor,
                               int* __restrict__ csr_src, float* __restrict__ csr_ea, int E_) {
    int e = blockIdx.x * 256 + threadIdx.x;
    if (e >= E_) return;
    int d = dst0[e];
    int p = atomicAdd(&cursor[d], 1);
    csr_src[p] = src0[e];
    csr_ea[p] = eattr[e];
}

// transpose Wl/Wr (3 each, 128x128) into Wt[6][j][k] = W[k][j]
__global__ void wtrans_kernel(const float* __restrict__ Wl, const float* __restrict__ Wr,
                              float* __restrict__ Wt) {
    int idx = blockIdx.x * 256 + threadIdx.x;
    if (idx >= 6 * 16384) return;
    int m = idx >> 14;
    int j = (idx >> 7) & 127;
    int k = idx & 127;
    const float* W = (m < 3) ? (Wl + m * 16384) : (Wr + (m - 3) * 16384);
    Wt[idx] = W[k * 128 + j];
}

// ---------------------------------------------------------------- input proj

__global__ void in_proj_kernel(const float* __restrict__ x, const float* __restrict__ W_in,
                               const float* __restrict__ b_in, float* __restrict__ h, int N_) {
    int idx = blockIdx.x * 256 + threadIdx.x;
    int n = idx >> 7, j = idx & 127;
    if (n >= N_) return;
    float acc = b_in[j];
    const float* xrow = x + n * 32;
#pragma unroll
    for (int k = 0; k < 32; ++k) acc += xrow[k] * W_in[k * 128 + j];
    h[n * 128 + j] = acc;
}

// ---------------------------------------------------------------- xl/xr GEMM
// block = 256 (4 waves), 32 rows/block. waves 0-1 -> xl, waves 2-3 -> xr;
// each wave 16 rows, lane owns cols (lane, lane+64). 32 accs/thread -> no spill.

__global__ __launch_bounds__(256) void proj_kernel(
    const float* __restrict__ h, const float* __restrict__ Wlt, const float* __restrict__ Wrt,
    const float* __restrict__ bl, const float* __restrict__ br,
    float* __restrict__ xl, float* __restrict__ xr, int N_) {
    __shared__ float hs[32 * 128];
    int t = threadIdx.x;
    int row0 = blockIdx.x * 32;
    {
        const float4* src = (const float4*)(h + (size_t)row0 * 128);
        float4* dst = (float4*)hs;
        int maxv = (N_ - row0) * 32;  // valid float4 count
#pragma unroll
        for (int i = 0; i < 4; ++i) {
            int o = i * 256 + t;
            int oc = o < maxv ? o : 0;
            dst[o] = src[oc];
        }
    }
    __syncthreads();
    int wave = t >> 6, lane = t & 63;
    bool isR = wave >= 2;
    int rbase = (wave & 1) * 16;
    const float* Wt = isR ? Wrt : Wlt;
    const float* bb = isR ? br : bl;
    float* out = isR ? xr : xl;
    const float* w0 = Wt + lane * 128;
    const float* w1 = Wt + (lane + 64) * 128;
    float acc0[16], acc1[16];
    float b0 = bb[lane], b1 = bb[lane + 64];
#pragma unroll
    for (int r = 0; r < 16; ++r) { acc0[r] = b0; acc1[r] = b1; }
    for (int k = 0; k < 128; k += 4) {
        float4 a = *(const float4*)(w0 + k);
        float4 b = *(const float4*)(w1 + k);
#pragma unroll
        for (int r = 0; r < 16; ++r) {
            float4 hv = *(const float4*)(&hs[(rbase + r) * 128 + k]);
            acc0[r] += hv.x * a.x + hv.y * a.y + hv.z * a.z + hv.w * a.w;
            acc1[r] += hv.x * b.x + hv.y * b.y + hv.z * b.z + hv.w * b.w;
        }
    }
#pragma unroll
    for (int r = 0; r < 16; ++r) {
        int row = row0 + rbase + r;
        if (row < N_) {
            out[row * 128 + lane] = acc0[r];
            out[row * 128 + lane + 64] = acc1[r];
        }
    }
}

// ---------------------------------------------------------------- per-node aggregation

__global__ __launch_bounds__(256) void aggregate_kernel(
    float* __restrict__ h, const float* __restrict__ xl, const float* __restrict__ xr,
    const int* __restrict__ rowstart, const int* __restrict__ csr_src,
    const float* __restrict__ csr_ea, const float* __restrict__ We,
    const float* __restrict__ att, const float* __restrict__ bc,
    const float* __restrict__ ln_g, const float* __restrict__ ln_b, int N_) {
    int wave = threadIdx.x >> 6, lane = threadIdx.x & 63;
    int n = blockIdx.x * 4 + wave;
    if (n >= N_) return;
    int c0 = lane * 2;
    int head = lane >> 4;
    float2 xr2 = *(const float2*)(xr + (size_t)n * 128 + c0);
    float2 we2 = *(const float2*)(We + c0);
    float2 at2 = *(const float2*)(att + head * 32 + (c0 & 31));
    int rs = rowstart[n], re = rowstart[n + 1];
    float m_run = -3.0e38f, d_run = 0.f;
    float accx = 0.f, accy = 0.f;
    for (int p = rs; p < re; ++p) {
        int s = csr_src[p];
        float eav = csr_ea[p];
        float2 xls = *(const float2*)(xl + (size_t)s * 128 + c0);
        float mx = xls.x + xr2.x + eav * we2.x;
        float my = xls.y + xr2.y + eav * we2.y;
        mx = mx > 0.f ? mx : NEG_SLOPE * mx;
        my = my > 0.f ? my : NEG_SLOPE * my;
        float part = mx * at2.x + my * at2.y;
        part += __shfl_xor(part, 1);
        part += __shfl_xor(part, 2);
        part += __shfl_xor(part, 4);
        part += __shfl_xor(part, 8);  // alpha for this head, all 16 lanes
        float nm = fmaxf(m_run, part);
        float sc = __expf(m_run - nm);
        float pe = __expf(part - nm);
        d_run = d_run * sc + pe;
        accx = accx * sc + pe * xls.x;
        accy = accy * sc + pe * xls.y;
        m_run = nm;
    }
    float inv = 1.f / d_run;
    float2 bc2 = *(const float2*)(bc + c0);
    float ox = accx * inv + bc2.x;
    float oy = accy * inv + bc2.y;
    ox = ox > 0.f ? ox : (__expf(ox) - 1.f);  // elu
    oy = oy > 0.f ? oy : (__expf(oy) - 1.f);
    float2 h2 = *(const float2*)(h + (size_t)n * 128 + c0);
    float tx = h2.x + ox, ty = h2.y + oy;
    float sum = tx + ty;
#pragma unroll
    for (int m = 1; m < 64; m <<= 1) sum += __shfl_xor(sum, m);
    float mu = sum * (1.f / 128.f);
    float dx = tx - mu, dy = ty - mu;
    float vs = dx * dx + dy * dy;
#pragma unroll
    for (int m = 1; m < 64; m <<= 1) vs += __shfl_xor(vs, m);
    float rstd = rsqrtf(vs * (1.f / 128.f) + LN_EPS);
    float2 g2 = *(const float2*)(ln_g + c0);
    float2 b2 = *(const float2*)(ln_b + c0);
    float2 hn;
    hn.x = dx * rstd * g2.x + b2.x;
    hn.y = dy * rstd * g2.y + b2.y;
    *(float2*)(h + (size_t)n * 128 + c0) = hn;
}

// ---------------------------------------------------------------- outputs
// wave = contiguous chunk of nodes; lane = 2 channels. gsum accumulated in
// registers per batch-run (batch is sorted) -> ~1 flush of 128 atomics per wave.

__global__ __launch_bounds__(256) void final_kernel(
    const float* __restrict__ h, const float* __restrict__ Wn, const float* __restrict__ bn,
    const int* __restrict__ batch, float* __restrict__ node_emb, float* __restrict__ h_out,
    float* __restrict__ gsum, float* __restrict__ gcnt, int N_, int chunk) {
    int wave_id = (blockIdx.x * 256 + threadIdx.x) >> 6;
    int lane = threadIdx.x & 63;
    int w0 = wave_id * chunk;
    if (w0 >= N_) return;
    int w1 = w0 + chunk; if (w1 > N_) w1 = N_;
    int c0 = lane * 2;
    float bnv = bn[lane];
    int cur_b = batch[w0];
    float accx = 0.f, accy = 0.f, cntf = 0.f;
    for (int n = w0; n < w1; ++n) {
        float2 h2 = *(const float2*)(h + (size_t)n * 128 + c0);
        *(float2*)(h_out + (size_t)n * 128 + c0) = h2;
        int b = batch[n];
        if (b != cur_b) {
            atomicAdd(&gsum[cur_b * 128 + c0], accx);
            atomicAdd(&gsum[cur_b * 128 + c0 + 1], accy);
            if (lane == 0) atomicAdd(gcnt + cur_b, cntf);
            accx = accy = cntf = 0.f;
            cur_b = b;
        }
        accx += h2.x; accy += h2.y; cntf += 1.f;
        float acc = bnv;
#pragma unroll 16
        for (int k2 = 0; k2 < 64; ++k2) {
            float hx = __shfl(h2.x, k2);
            float hy = __shfl(h2.y, k2);
            acc += hx * Wn[(2 * k2) * 64 + lane] + hy * Wn[(2 * k2 + 1) * 64 + lane];
        }
        node_emb[(size_t)n * 64 + lane] = acc;
    }
    atomicAdd(&gsum[cur_b * 128 + c0], accx);
    atomicAdd(&gsum[cur_b * 128 + c0 + 1], accy);
    if (lane == 0) atomicAdd(gcnt + cur_b, cntf);
}

__global__ void graph_kernel(const float* __restrict__ gsum, const float* __restrict__ gcnt,
                             const float* __restrict__ Wg1, const float* __restrict__ bg1,
                             const float* __restrict__ Wg2, const float* __restrict__ bg2,
                             float* __restrict__ graph_emb) {
    __shared__ float gm[8 * 128];
    __shared__ float t1[8 * 128];
    int t = threadIdx.x;
    for (int i = t; i < 1024; i += 256) {
        int b = i >> 7;
        float c = gcnt[b];
        c = c > 1.f ? c : 1.f;
        gm[i] = gsum[i] / c;
    }
    __syncthreads();
    for (int i = t; i < 1024; i += 256) {
        int r = i >> 7, j = i & 127;
        float acc = bg1[j];
        for (int k = 0; k < 128; ++k) acc += gm[r * 128 + k] * Wg1[k * 128 + j];
        t1[i] = acc > 0.f ? acc : (__expf(acc) - 1.f);
    }
    __syncthreads();
    for (int i = t; i < 512; i += 256) {
        int r = i >> 6, j = i & 63;
        float acc = bg2[j];
        for (int k = 0; k < 128; ++k) acc += t1[r * 128 + k] * Wg2[k * 64 + j];
        graph_emb[r * 64 + j] = acc;
    }
}

// ---------------------------------------------------------------- launch

extern "C" void kernel_launch(void* const* d_in, const int* in_sizes, int n_in,
                              void* d_out, int out_size, void* d_ws, size_t ws_size,
                              hipStream_t stream) {
    const float* x         = (const float*)d_in[0];
    const int*   edge_index= (const int*)d_in[1];
    const float* edge_attr = (const float*)d_in[2];
    const int*   batch     = (const int*)d_in[3];
    const float* W_in      = (const float*)d_in[4];
    const float* b_in      = (const float*)d_in[5];
    const float* Wl        = (const float*)d_in[6];
    const float* bl        = (const float*)d_in[7];
    const float* Wr        = (const float*)d_in[8];
    const float* br        = (const float*)d_in[9];
    const float* We        = (const float*)d_in[10];
    const float* att       = (const float*)d_in[11];
    const float* bc        = (const float*)d_in[12];
    const float* ln_g      = (const float*)d_in[13];
    const float* ln_b      = (const float*)d_in[14];
    const float* Wn        = (const float*)d_in[15];
    const float* bn        = (const float*)d_in[16];
    const float* Wg1       = (const float*)d_in[17];
    const float* bg1       = (const float*)d_in[18];
    const float* Wg2       = (const float*)d_in[19];
    const float* bg2       = (const float*)d_in[20];

    const int N_ = in_sizes[3];   // batch is (N,)
    const int E_ = in_sizes[2];   // edge_attr is (E,1)

    const int* src0 = edge_index;
    const int* dst0 = edge_index + E_;

    float* ws = (float*)d_ws;
    float* h      = ws;                              // N*128
    float* xl     = h + (size_t)N_ * 128;            // N*128
    float* xr     = xl + (size_t)N_ * 128;           // N*128
    float* csr_ea = xr + (size_t)N_ * 128;           // E+N
    float* Wt     = csr_ea + (size_t)(E_ + N_);      // 6*16384
    float* gsum   = Wt + 6 * 16384;                  // 1024
    float* gcnt   = gsum + 1024;                     // 16 (8 used)
    float* easum  = gcnt + 16;                       // N
    int* cnt      = (int*)(easum + N_);              // N
    int* rowstart = cnt + N_;                        // N+1
    int* cursor   = rowstart + N_ + 1;               // N
    int* csr_src  = cursor + N_;                     // E+N

    float* out_f     = (float*)d_out;
    float* node_emb  = out_f;                               // N*64
    float* graph_emb = out_f + (size_t)N_ * 64;             // 8*64
    float* h_out     = out_f + (size_t)N_ * 64 + 8 * 64;    // N*128

    hipMemsetAsync(cnt, 0, N_ * sizeof(int), stream);
    hipMemsetAsync(easum, 0, N_ * sizeof(float), stream);
    hipMemsetAsync(gsum, 0, (1024 + 16) * sizeof(float), stream);

    wtrans_kernel<<<(6 * 16384 + 255) / 256, 256, 0, stream>>>(Wl, Wr, Wt);
    count_kernel<<<(E_ + 255) / 256, 256, 0, stream>>>(dst0, edge_attr, cnt, easum, E_);
    scan_kernel<<<1, 1024, 0, stream>>>(cnt, rowstart, N_);
    selfloop_kernel<<<(N_ + 255) / 256, 256, 0, stream>>>(cnt, easum, rowstart, cursor,
                                                          csr_src, csr_ea, N_);
    scatter_kernel<<<(E_ + 255) / 256, 256, 0, stream>>>(src0, dst0, edge_attr, cursor,
                                                         csr_src, csr_ea, E_);
    in_proj_kernel<<<((N_ * 128) + 255) / 256, 256, 0, stream>>>(x, W_in, b_in, h, N_);

    for (int l = 0; l < 3; ++l) {
        proj_kernel<<<(N_ + 31) / 32, 256, 0, stream>>>(
            h, Wt + l * 16384, Wt + (3 + l) * 16384, bl + l * 128, br + l * 128, xl, xr, N_);
        aggregate_kernel<<<(N_ + 3) / 4, 256, 0, stream>>>(
            h, xl, xr, rowstart, csr_src, csr_ea, We + l * 128, att + l * 128,
            bc + l * 128, ln_g + l * 128, ln_b + l * 128, N_);
    }

    // 2048 waves, each a contiguous node chunk (batch sorted -> ~1 gsum flush/wave)
    {
        int total_waves = 2048;
        int chunk = (N_ + total_waves - 1) / total_waves;
        final_kernel<<<total_waves / 4, 256, 0, stream>>>(h, Wn, bn, batch, node_emb, h_out,
                                                          gsum, gcnt, N_, chunk);
    }
    graph_kernel<<<1, 256, 0, stream>>>(gsum, gcnt, Wg1, bg1, Wg2, bg2, graph_emb);
}

// Round 4
// 956.931 us; speedup vs baseline: 3.4032x; 1.1414x over previous
//
#include <hip/hip_runtime.h>

#define NEG_SLOPE 0.2f
#define LN_EPS 1e-5f

// ---------------------------------------------------------------- prep kernels

__global__ void count_kernel(const int* __restrict__ dst0, const float* __restrict__ eattr,
                             int* __restrict__ cnt, float* __restrict__ easum, int E_) {
    int e = blockIdx.x * 256 + threadIdx.x;
    if (e >= E_) return;
    int d = dst0[e];
    atomicAdd(&cnt[d], 1);
    atomicAdd(&easum[d], eattr[e]);
}

__global__ void scan_kernel(const int* __restrict__ cnt, int* __restrict__ rowstart, int N_) {
    __shared__ int lds[1024];
    int t = threadIdx.x;
    int chunk = (N_ + 1023) >> 10;
    int begin = t * chunk;
    int end = begin + chunk; if (end > N_) end = N_; if (begin > N_) begin = N_;
    int s = 0;
    for (int i = begin; i < end; ++i) s += cnt[i] + 1;
    lds[t] = s;
    __syncthreads();
    for (int off = 1; off < 1024; off <<= 1) {
        int v = (t >= off) ? lds[t - off] : 0;
        __syncthreads();
        lds[t] += v;
        __syncthreads();
    }
    int run = lds[t] - s;  // exclusive base
    for (int i = begin; i < end; ++i) { rowstart[i] = run; run += cnt[i] + 1; }
    if (t == 1023) rowstart[N_] = lds[1023];
}

__global__ void selfloop_kernel(const int* __restrict__ cnt, const float* __restrict__ easum,
                                const int* __restrict__ rowstart, int* __restrict__ cursor,
                                int2* __restrict__ csr, int N_) {
    int n = blockIdx.x * 256 + threadIdx.x;
    if (n >= N_) return;
    int rs = rowstart[n];
    int c = cnt[n];
    float ea = easum[n] / (float)(c > 1 ? c : 1);
    csr[rs] = make_int2(n, __float_as_int(ea));
    cursor[n] = rs + 1;
}

__global__ void scatter_kernel(const int* __restrict__ src0, const int* __restrict__ dst0,
                               const float* __restrict__ eattr, int* __restrict__ cursor,
                               int2* __restrict__ csr, int E_) {
    int e = blockIdx.x * 256 + threadIdx.x;
    if (e >= E_) return;
    int d = dst0[e];
    int p = atomicAdd(&cursor[d], 1);
    csr[p] = make_int2(src0[e], __float_as_int(eattr[e]));
}

// transpose Wl/Wr (3 each, 128x128) into Wt[6][j][k] = W[k][j]
__global__ void wtrans_kernel(const float* __restrict__ Wl, const float* __restrict__ Wr,
                              float* __restrict__ Wt) {
    int idx = blockIdx.x * 256 + threadIdx.x;
    if (idx >= 6 * 16384) return;
    int m = idx >> 14;
    int j = (idx >> 7) & 127;
    int k = idx & 127;
    const float* W = (m < 3) ? (Wl + m * 16384) : (Wr + (m - 3) * 16384);
    Wt[idx] = W[k * 128 + j];
}

// ---------------------------------------------------------------- input proj

__global__ void in_proj_kernel(const float* __restrict__ x, const float* __restrict__ W_in,
                               const float* __restrict__ b_in, float* __restrict__ h, int N_) {
    int idx = blockIdx.x * 256 + threadIdx.x;
    int n = idx >> 7, j = idx & 127;
    if (n >= N_) return;
    float acc = b_in[j];
    const float* xrow = x + n * 32;
#pragma unroll
    for (int k = 0; k < 32; ++k) acc += xrow[k] * W_in[k * 128 + j];
    h[n * 128 + j] = acc;
}

// ---------------------------------------------------------------- xl/xr GEMM
// block = 256 (4 waves), 32 rows/block. waves 0-1 -> xl, waves 2-3 -> xr;
// each wave 16 rows, lane owns cols (lane, lane+64). 32 accs/thread -> no spill.

__global__ __launch_bounds__(256) void proj_kernel(
    const float* __restrict__ h, const float* __restrict__ Wlt, const float* __restrict__ Wrt,
    const float* __restrict__ bl, const float* __restrict__ br,
    float* __restrict__ xl, float* __restrict__ xr, int N_) {
    __shared__ float hs[32 * 128];
    int t = threadIdx.x;
    int row0 = blockIdx.x * 32;
    {
        const float4* src = (const float4*)(h + (size_t)row0 * 128);
        float4* dst = (float4*)hs;
        int maxv = (N_ - row0) * 32;  // valid float4 count
#pragma unroll
        for (int i = 0; i < 4; ++i) {
            int o = i * 256 + t;
            int oc = o < maxv ? o : 0;
            dst[o] = src[oc];
        }
    }
    __syncthreads();
    int wave = t >> 6, lane = t & 63;
    bool isR = wave >= 2;
    int rbase = (wave & 1) * 16;
    const float* Wt = isR ? Wrt : Wlt;
    const float* bb = isR ? br : bl;
    float* out = isR ? xr : xl;
    const float* w0 = Wt + lane * 128;
    const float* w1 = Wt + (lane + 64) * 128;
    float acc0[16], acc1[16];
    float b0 = bb[lane], b1 = bb[lane + 64];
#pragma unroll
    for (int r = 0; r < 16; ++r) { acc0[r] = b0; acc1[r] = b1; }
    for (int k = 0; k < 128; k += 4) {
        float4 a = *(const float4*)(w0 + k);
        float4 b = *(const float4*)(w1 + k);
#pragma unroll
        for (int r = 0; r < 16; ++r) {
            float4 hv = *(const float4*)(&hs[(rbase + r) * 128 + k]);
            acc0[r] += hv.x * a.x + hv.y * a.y + hv.z * a.z + hv.w * a.w;
            acc1[r] += hv.x * b.x + hv.y * b.y + hv.z * b.z + hv.w * b.w;
        }
    }
#pragma unroll
    for (int r = 0; r < 16; ++r) {
        int row = row0 + rbase + r;
        if (row < N_) {
            out[row * 128 + lane] = acc0[r];
            out[row * 128 + lane + 64] = acc1[r];
        }
    }
}

// ---------------------------------------------------------------- per-node aggregation
// DPP 16-lane head reduce: xor1 (quad_perm 0xB1), xor2 (quad_perm 0x4E),
// xor7 (row_half_mirror 0x141), xor15 (row_mirror 0x140) -- full-rate VALU.

__device__ __forceinline__ float head16_sum(float x) {
    int v;
    v = __builtin_amdgcn_update_dpp(0, __float_as_int(x), 0xB1, 0xF, 0xF, true);
    x += __int_as_float(v);
    v = __builtin_amdgcn_update_dpp(0, __float_as_int(x), 0x4E, 0xF, 0xF, true);
    x += __int_as_float(v);
    v = __builtin_amdgcn_update_dpp(0, __float_as_int(x), 0x141, 0xF, 0xF, true);
    x += __int_as_float(v);
    v = __builtin_amdgcn_update_dpp(0, __float_as_int(x), 0x140, 0xF, 0xF, true);
    x += __int_as_float(v);
    return x;
}

// one wave per node; lane = 2 channels; defer-max online softmax (exact via
// shift invariance); two independent edge states for ILP, merged at the end.

__global__ __launch_bounds__(256) void aggregate_kernel(
    float* __restrict__ h, const float* __restrict__ xl, const float* __restrict__ xr,
    const int* __restrict__ rowstart, const int2* __restrict__ csr,
    const float* __restrict__ We, const float* __restrict__ att, const float* __restrict__ bc,
    const float* __restrict__ ln_g, const float* __restrict__ ln_b, int N_) {
    int wave = threadIdx.x >> 6, lane = threadIdx.x & 63;
    int n = blockIdx.x * 4 + wave;
    if (n >= N_) return;
    int c0 = lane * 2;
    int head = lane >> 4;
    float2 xr2 = *(const float2*)(xr + (size_t)n * 128 + c0);
    float2 we2 = *(const float2*)(We + c0);
    float2 at2 = *(const float2*)(att + head * 32 + (c0 & 31));
    int rs = rowstart[n], re = rowstart[n + 1];
    float m0 = -3.0e38f, d0 = 0.f, ax0 = 0.f, ay0 = 0.f;
    float m1 = -3.0e38f, d1 = 0.f, ax1 = 0.f, ay1 = 0.f;
    int p = rs;
    for (; p + 2 <= re; p += 2) {
        int2 e0 = csr[p];
        int2 e1 = csr[p + 1];
        float2 xa = *(const float2*)(xl + (size_t)e0.x * 128 + c0);
        float2 xb = *(const float2*)(xl + (size_t)e1.x * 128 + c0);
        float ea0 = __int_as_float(e0.y), ea1 = __int_as_float(e1.y);
        float mx0 = xa.x + fmaf(ea0, we2.x, xr2.x);
        float my0 = xa.y + fmaf(ea0, we2.y, xr2.y);
        mx0 = fmaxf(mx0, NEG_SLOPE * mx0);
        my0 = fmaxf(my0, NEG_SLOPE * my0);
        float part0 = head16_sum(mx0 * at2.x + my0 * at2.y);
        float mx1 = xb.x + fmaf(ea1, we2.x, xr2.x);
        float my1 = xb.y + fmaf(ea1, we2.y, xr2.y);
        mx1 = fmaxf(mx1, NEG_SLOPE * mx1);
        my1 = fmaxf(my1, NEG_SLOPE * my1);
        float part1 = head16_sum(mx1 * at2.x + my1 * at2.y);
        if (__any(part0 > m0 + 8.f)) {
            float nm = fmaxf(m0, part0);
            float sc = __expf(m0 - nm);
            d0 *= sc; ax0 *= sc; ay0 *= sc; m0 = nm;
        }
        float pe0 = __expf(part0 - m0);
        d0 += pe0;
        ax0 = fmaf(pe0, xa.x, ax0);
        ay0 = fmaf(pe0, xa.y, ay0);
        if (__any(part1 > m1 + 8.f)) {
            float nm = fmaxf(m1, part1);
            float sc = __expf(m1 - nm);
            d1 *= sc; ax1 *= sc; ay1 *= sc; m1 = nm;
        }
        float pe1 = __expf(part1 - m1);
        d1 += pe1;
        ax1 = fmaf(pe1, xb.x, ax1);
        ay1 = fmaf(pe1, xb.y, ay1);
    }
    if (p < re) {
        int2 e0 = csr[p];
        float2 xa = *(const float2*)(xl + (size_t)e0.x * 128 + c0);
        float ea0 = __int_as_float(e0.y);
        float mx0 = xa.x + fmaf(ea0, we2.x, xr2.x);
        float my0 = xa.y + fmaf(ea0, we2.y, xr2.y);
        mx0 = fmaxf(mx0, NEG_SLOPE * mx0);
        my0 = fmaxf(my0, NEG_SLOPE * my0);
        float part0 = head16_sum(mx0 * at2.x + my0 * at2.y);
        if (__any(part0 > m0 + 8.f)) {
            float nm = fmaxf(m0, part0);
            float sc = __expf(m0 - nm);
            d0 *= sc; ax0 *= sc; ay0 *= sc; m0 = nm;
        }
        float pe0 = __expf(part0 - m0);
        d0 += pe0;
        ax0 = fmaf(pe0, xa.x, ax0);
        ay0 = fmaf(pe0, xa.y, ay0);
    }
    // merge the two online states (exact)
    float mm = fmaxf(m0, m1);
    float s0 = __expf(m0 - mm), s1 = __expf(m1 - mm);
    float den = d0 * s0 + d1 * s1;
    float accx = ax0 * s0 + ax1 * s1;
    float accy = ay0 * s0 + ay1 * s1;
    float inv = 1.f / den;
    float2 bc2 = *(const float2*)(bc + c0);
    float ox = accx * inv + bc2.x;
    float oy = accy * inv + bc2.y;
    ox = ox > 0.f ? ox : (__expf(ox) - 1.f);  // elu
    oy = oy > 0.f ? oy : (__expf(oy) - 1.f);
    float2 h2 = *(const float2*)(h + (size_t)n * 128 + c0);
    float tx = h2.x + ox, ty = h2.y + oy;
    float sum = tx + ty;
#pragma unroll
    for (int m = 1; m < 64; m <<= 1) sum += __shfl_xor(sum, m);
    float mu = sum * (1.f / 128.f);
    float dx = tx - mu, dy = ty - mu;
    float vs = dx * dx + dy * dy;
#pragma unroll
    for (int m = 1; m < 64; m <<= 1) vs += __shfl_xor(vs, m);
    float rstd = rsqrtf(vs * (1.f / 128.f) + LN_EPS);
    float2 g2 = *(const float2*)(ln_g + c0);
    float2 b2 = *(const float2*)(ln_b + c0);
    float2 hn;
    hn.x = dx * rstd * g2.x + b2.x;
    hn.y = dy * rstd * g2.y + b2.y;
    *(float2*)(h + (size_t)n * 128 + c0) = hn;
}

// ---------------------------------------------------------------- outputs
// wave = contiguous chunk of nodes; lane = 2 channels. gsum accumulated in
// registers per batch-run (batch is sorted) -> ~1 flush of 128 atomics per wave.

__global__ __launch_bounds__(256) void final_kernel(
    const float* __restrict__ h, const float* __restrict__ Wn, const float* __restrict__ bn,
    const int* __restrict__ batch, float* __restrict__ node_emb, float* __restrict__ h_out,
    float* __restrict__ gsum, float* __restrict__ gcnt, int N_, int chunk) {
    int wave_id = (blockIdx.x * 256 + threadIdx.x) >> 6;
    int lane = threadIdx.x & 63;
    int w0 = wave_id * chunk;
    if (w0 >= N_) return;
    int w1 = w0 + chunk; if (w1 > N_) w1 = N_;
    int c0 = lane * 2;
    float bnv = bn[lane];
    int cur_b = batch[w0];
    float accx = 0.f, accy = 0.f, cntf = 0.f;
    for (int n = w0; n < w1; ++n) {
        float2 h2 = *(const float2*)(h + (size_t)n * 128 + c0);
        *(float2*)(h_out + (size_t)n * 128 + c0) = h2;
        int b = batch[n];
        if (b != cur_b) {
            atomicAdd(&gsum[cur_b * 128 + c0], accx);
            atomicAdd(&gsum[cur_b * 128 + c0 + 1], accy);
            if (lane == 0) atomicAdd(gcnt + cur_b, cntf);
            accx = accy = cntf = 0.f;
            cur_b = b;
        }
        accx += h2.x; accy += h2.y; cntf += 1.f;
        float acc = bnv;
#pragma unroll 16
        for (int k2 = 0; k2 < 64; ++k2) {
            float hx = __shfl(h2.x, k2);
            float hy = __shfl(h2.y, k2);
            acc += hx * Wn[(2 * k2) * 64 + lane] + hy * Wn[(2 * k2 + 1) * 64 + lane];
        }
        node_emb[(size_t)n * 64 + lane] = acc;
    }
    atomicAdd(&gsum[cur_b * 128 + c0], accx);
    atomicAdd(&gsum[cur_b * 128 + c0 + 1], accy);
    if (lane == 0) atomicAdd(gcnt + cur_b, cntf);
}

__global__ void graph_kernel(const float* __restrict__ gsum, const float* __restrict__ gcnt,
                             const float* __restrict__ Wg1, const float* __restrict__ bg1,
                             const float* __restrict__ Wg2, const float* __restrict__ bg2,
                             float* __restrict__ graph_emb) {
    __shared__ float gm[8 * 128];
    __shared__ float t1[8 * 128];
    int t = threadIdx.x;
    for (int i = t; i < 1024; i += 256) {
        int b = i >> 7;
        float c = gcnt[b];
        c = c > 1.f ? c : 1.f;
        gm[i] = gsum[i] / c;
    }
    __syncthreads();
    for (int i = t; i < 1024; i += 256) {
        int r = i >> 7, j = i & 127;
        float acc = bg1[j];
        for (int k = 0; k < 128; ++k) acc += gm[r * 128 + k] * Wg1[k * 128 + j];
        t1[i] = acc > 0.f ? acc : (__expf(acc) - 1.f);
    }
    __syncthreads();
    for (int i = t; i < 512; i += 256) {
        int r = i >> 6, j = i & 63;
        float acc = bg2[j];
        for (int k = 0; k < 128; ++k) acc += t1[r * 128 + k] * Wg2[k * 64 + j];
        graph_emb[r * 64 + j] = acc;
    }
}

// ---------------------------------------------------------------- launch

extern "C" void kernel_launch(void* const* d_in, const int* in_sizes, int n_in,
                              void* d_out, int out_size, void* d_ws, size_t ws_size,
                              hipStream_t stream) {
    const float* x         = (const float*)d_in[0];
    const int*   edge_index= (const int*)d_in[1];
    const float* edge_attr = (const float*)d_in[2];
    const int*   batch     = (const int*)d_in[3];
    const float* W_in      = (const float*)d_in[4];
    const float* b_in      = (const float*)d_in[5];
    const float* Wl        = (const float*)d_in[6];
    const float* bl        = (const float*)d_in[7];
    const float* Wr        = (const float*)d_in[8];
    const float* br        = (const float*)d_in[9];
    const float* We        = (const float*)d_in[10];
    const float* att       = (const float*)d_in[11];
    const float* bc        = (const float*)d_in[12];
    const float* ln_g      = (const float*)d_in[13];
    const float* ln_b      = (const float*)d_in[14];
    const float* Wn        = (const float*)d_in[15];
    const float* bn        = (const float*)d_in[16];
    const float* Wg1       = (const float*)d_in[17];
    const float* bg1       = (const float*)d_in[18];
    const float* Wg2       = (const float*)d_in[19];
    const float* bg2       = (const float*)d_in[20];

    const int N_ = in_sizes[3];   // batch is (N,)
    const int E_ = in_sizes[2];   // edge_attr is (E,1)

    const int* src0 = edge_index;
    const int* dst0 = edge_index + E_;

    float* ws = (float*)d_ws;
    float* h      = ws;                              // N*128
    float* xl     = h + (size_t)N_ * 128;            // N*128
    float* xr     = xl + (size_t)N_ * 128;           // N*128
    float* Wt     = xr + (size_t)N_ * 128;           // 6*16384
    float* gsum   = Wt + 6 * 16384;                  // 1024
    float* gcnt   = gsum + 1024;                     // 16 (8 used)
    float* easum  = gcnt + 16;                       // N
    int* cnt      = (int*)(easum + N_);              // N
    int* rowstart = cnt + N_;                        // N+2 (pad for int2 align)
    int* cursor   = rowstart + N_ + 2;               // N
    int2* csr     = (int2*)(cursor + N_);            // E+N (8B aligned)

    float* out_f     = (float*)d_out;
    float* node_emb  = out_f;                               // N*64
    float* graph_emb = out_f + (size_t)N_ * 64;             // 8*64
    float* h_out     = out_f + (size_t)N_ * 64 + 8 * 64;    // N*128

    // gsum, gcnt, easum, cnt are contiguous -> one memset
    hipMemsetAsync(gsum, 0, (1024 + 16 + 2 * (size_t)N_) * sizeof(float), stream);

    wtrans_kernel<<<(6 * 16384 + 255) / 256, 256, 0, stream>>>(Wl, Wr, Wt);
    count_kernel<<<(E_ + 255) / 256, 256, 0, stream>>>(dst0, edge_attr, cnt, easum, E_);
    scan_kernel<<<1, 1024, 0, stream>>>(cnt, rowstart, N_);
    selfloop_kernel<<<(N_ + 255) / 256, 256, 0, stream>>>(cnt, easum, rowstart, cursor,
                                                          csr, N_);
    scatter_kernel<<<(E_ + 255) / 256, 256, 0, stream>>>(src0, dst0, edge_attr, cursor,
                                                         csr, E_);
    in_proj_kernel<<<((N_ * 128) + 255) / 256, 256, 0, stream>>>(x, W_in, b_in, h, N_);

    for (int l = 0; l < 3; ++l) {
        proj_kernel<<<(N_ + 31) / 32, 256, 0, stream>>>(
            h, Wt + l * 16384, Wt + (3 + l) * 16384, bl + l * 128, br + l * 128, xl, xr, N_);
        aggregate_kernel<<<(N_ + 3) / 4, 256, 0, stream>>>(
            h, xl, xr, rowstart, csr, We + l * 128, att + l * 128,
            bc + l * 128, ln_g + l * 128, ln_b + l * 128, N_);
    }

    // 2048 waves, each a contiguous node chunk (batch sorted -> ~1 gsum flush/wave)
    {
        int total_waves = 2048;
        int chunk = (N_ + total_waves - 1) / total_waves;
        final_kernel<<<total_waves / 4, 256, 0, stream>>>(h, Wn, bn, batch, node_emb, h_out,
                                                          gsum, gcnt, N_, chunk);
    }
    graph_kernel<<<1, 256, 0, stream>>>(gsum, gcnt, Wg1, bg1, Wg2, bg2, graph_emb);
}

// Round 5
// 919.856 us; speedup vs baseline: 3.5403x; 1.0403x over previous
//
#include <hip/hip_runtime.h>

#define NEG_SLOPE 0.2f
#define LN_EPS 1e-5f

// ---------------------------------------------------------------- prep kernels

__global__ void count_kernel(const int* __restrict__ dst0, const float* __restrict__ eattr,
                             int* __restrict__ cnt, float* __restrict__ easum, int E_) {
    int e = blockIdx.x * 256 + threadIdx.x;
    if (e >= E_) return;
    int d = dst0[e];
    atomicAdd(&cnt[d], 1);
    atomicAdd(&easum[d], eattr[e]);
}

__global__ void scan_kernel(const int* __restrict__ cnt, int* __restrict__ rowstart, int N_) {
    __shared__ int lds[1024];
    int t = threadIdx.x;
    int chunk = (N_ + 1023) >> 10;
    int begin = t * chunk;
    int end = begin + chunk; if (end > N_) end = N_; if (begin > N_) begin = N_;
    int s = 0;
    for (int i = begin; i < end; ++i) s += cnt[i] + 1;
    lds[t] = s;
    __syncthreads();
    for (int off = 1; off < 1024; off <<= 1) {
        int v = (t >= off) ? lds[t - off] : 0;
        __syncthreads();
        lds[t] += v;
        __syncthreads();
    }
    int run = lds[t] - s;  // exclusive base
    for (int i = begin; i < end; ++i) { rowstart[i] = run; run += cnt[i] + 1; }
    if (t == 1023) rowstart[N_] = lds[1023];
}

__global__ void selfloop_kernel(const int* __restrict__ cnt, const float* __restrict__ easum,
                                const int* __restrict__ rowstart, int* __restrict__ cursor,
                                int2* __restrict__ csr, int N_) {
    int n = blockIdx.x * 256 + threadIdx.x;
    if (n >= N_) return;
    int rs = rowstart[n];
    int c = cnt[n];
    float ea = easum[n] / (float)(c > 1 ? c : 1);
    csr[rs] = make_int2(n, __float_as_int(ea));
    cursor[n] = rs + 1;
}

__global__ void scatter_kernel(const int* __restrict__ src0, const int* __restrict__ dst0,
                               const float* __restrict__ eattr, int* __restrict__ cursor,
                               int2* __restrict__ csr, int E_) {
    int e = blockIdx.x * 256 + threadIdx.x;
    if (e >= E_) return;
    int d = dst0[e];
    int p = atomicAdd(&cursor[d], 1);
    csr[p] = make_int2(src0[e], __float_as_int(eattr[e]));
}

// transpose Wl/Wr (3 each, 128x128) into Wt[6][j][k] = W[k][j]
__global__ void wtrans_kernel(const float* __restrict__ Wl, const float* __restrict__ Wr,
                              float* __restrict__ Wt) {
    int idx = blockIdx.x * 256 + threadIdx.x;
    if (idx >= 6 * 16384) return;
    int m = idx >> 14;
    int j = (idx >> 7) & 127;
    int k = idx & 127;
    const float* W = (m < 3) ? (Wl + m * 16384) : (Wr + (m - 3) * 16384);
    Wt[idx] = W[k * 128 + j];
}

// ---------------------------------------------------------------- input proj

__global__ void in_proj_kernel(const float* __restrict__ x, const float* __restrict__ W_in,
                               const float* __restrict__ b_in, float* __restrict__ h, int N_) {
    int idx = blockIdx.x * 256 + threadIdx.x;
    int n = idx >> 7, j = idx & 127;
    if (n >= N_) return;
    float acc = b_in[j];
    const float* xrow = x + n * 32;
#pragma unroll
    for (int k = 0; k < 32; ++k) acc += xrow[k] * W_in[k * 128 + j];
    h[n * 128 + j] = acc;
}

// ---------------------------------------------------------------- xl/xr GEMM
// block = 256 (4 waves), 32 rows/block. waves 0-1 -> xl, waves 2-3 -> xr;
// each wave 16 rows, lane owns cols (lane, lane+64). 32 accs/thread -> no spill.

__global__ __launch_bounds__(256) void proj_kernel(
    const float* __restrict__ h, const float* __restrict__ Wlt, const float* __restrict__ Wrt,
    const float* __restrict__ bl, const float* __restrict__ br,
    float* __restrict__ xl, float* __restrict__ xr, int N_) {
    __shared__ float hs[32 * 128];
    int t = threadIdx.x;
    int row0 = blockIdx.x * 32;
    {
        const float4* src = (const float4*)(h + (size_t)row0 * 128);
        float4* dst = (float4*)hs;
        int maxv = (N_ - row0) * 32;  // valid float4 count
#pragma unroll
        for (int i = 0; i < 4; ++i) {
            int o = i * 256 + t;
            int oc = o < maxv ? o : 0;
            dst[o] = src[oc];
        }
    }
    __syncthreads();
    int wave = t >> 6, lane = t & 63;
    bool isR = wave >= 2;
    int rbase = (wave & 1) * 16;
    const float* Wt = isR ? Wrt : Wlt;
    const float* bb = isR ? br : bl;
    float* out = isR ? xr : xl;
    const float* w0 = Wt + lane * 128;
    const float* w1 = Wt + (lane + 64) * 128;
    float acc0[16], acc1[16];
    float b0 = bb[lane], b1 = bb[lane + 64];
#pragma unroll
    for (int r = 0; r < 16; ++r) { acc0[r] = b0; acc1[r] = b1; }
    for (int k = 0; k < 128; k += 4) {
        float4 a = *(const float4*)(w0 + k);
        float4 b = *(const float4*)(w1 + k);
#pragma unroll
        for (int r = 0; r < 16; ++r) {
            float4 hv = *(const float4*)(&hs[(rbase + r) * 128 + k]);
            acc0[r] += hv.x * a.x + hv.y * a.y + hv.z * a.z + hv.w * a.w;
            acc1[r] += hv.x * b.x + hv.y * b.y + hv.z * b.z + hv.w * b.w;
        }
    }
#pragma unroll
    for (int r = 0; r < 16; ++r) {
        int row = row0 + rbase + r;
        if (row < N_) {
            out[row * 128 + lane] = acc0[r];
            out[row * 128 + lane + 64] = acc1[r];
        }
    }
}

// ---------------------------------------------------------------- per-node aggregation
// DPP 16-lane head reduce: xor1 (quad_perm 0xB1), xor2 (quad_perm 0x4E),
// xor7 (row_half_mirror 0x141), xor15 (row_mirror 0x140) -- full-rate VALU.

__device__ __forceinline__ float head16_sum(float x) {
    int v;
    v = __builtin_amdgcn_update_dpp(0, __float_as_int(x), 0xB1, 0xF, 0xF, true);
    x += __int_as_float(v);
    v = __builtin_amdgcn_update_dpp(0, __float_as_int(x), 0x4E, 0xF, 0xF, true);
    x += __int_as_float(v);
    v = __builtin_amdgcn_update_dpp(0, __float_as_int(x), 0x141, 0xF, 0xF, true);
    x += __int_as_float(v);
    v = __builtin_amdgcn_update_dpp(0, __float_as_int(x), 0x140, 0xF, 0xF, true);
    x += __int_as_float(v);
    return x;
}

// one wave per node; lane = 2 channels; defer-max online softmax (exact via
// shift invariance); two independent edge states for ILP, merged at the end.
// h_out != nullptr (last layer): dual-store the normalized h.

__global__ __launch_bounds__(256) void aggregate_kernel(
    float* __restrict__ h, const float* __restrict__ xl, const float* __restrict__ xr,
    const int* __restrict__ rowstart, const int2* __restrict__ csr,
    const float* __restrict__ We, const float* __restrict__ att, const float* __restrict__ bc,
    const float* __restrict__ ln_g, const float* __restrict__ ln_b,
    float* __restrict__ h_out, int N_) {
    int wave = threadIdx.x >> 6, lane = threadIdx.x & 63;
    int n = blockIdx.x * 4 + wave;
    if (n >= N_) return;
    int c0 = lane * 2;
    int head = lane >> 4;
    float2 xr2 = *(const float2*)(xr + (size_t)n * 128 + c0);
    float2 we2 = *(const float2*)(We + c0);
    float2 at2 = *(const float2*)(att + head * 32 + (c0 & 31));
    int rs = rowstart[n], re = rowstart[n + 1];
    float m0 = -3.0e38f, d0 = 0.f, ax0 = 0.f, ay0 = 0.f;
    float m1 = -3.0e38f, d1 = 0.f, ax1 = 0.f, ay1 = 0.f;
    int p = rs;
    for (; p + 2 <= re; p += 2) {
        int2 e0 = csr[p];
        int2 e1 = csr[p + 1];
        float2 xa = *(const float2*)(xl + (size_t)e0.x * 128 + c0);
        float2 xb = *(const float2*)(xl + (size_t)e1.x * 128 + c0);
        float ea0 = __int_as_float(e0.y), ea1 = __int_as_float(e1.y);
        float mx0 = xa.x + fmaf(ea0, we2.x, xr2.x);
        float my0 = xa.y + fmaf(ea0, we2.y, xr2.y);
        mx0 = fmaxf(mx0, NEG_SLOPE * mx0);
        my0 = fmaxf(my0, NEG_SLOPE * my0);
        float part0 = head16_sum(mx0 * at2.x + my0 * at2.y);
        float mx1 = xb.x + fmaf(ea1, we2.x, xr2.x);
        float my1 = xb.y + fmaf(ea1, we2.y, xr2.y);
        mx1 = fmaxf(mx1, NEG_SLOPE * mx1);
        my1 = fmaxf(my1, NEG_SLOPE * my1);
        float part1 = head16_sum(mx1 * at2.x + my1 * at2.y);
        if (__any(part0 > m0 + 8.f)) {
            float nm = fmaxf(m0, part0);
            float sc = __expf(m0 - nm);
            d0 *= sc; ax0 *= sc; ay0 *= sc; m0 = nm;
        }
        float pe0 = __expf(part0 - m0);
        d0 += pe0;
        ax0 = fmaf(pe0, xa.x, ax0);
        ay0 = fmaf(pe0, xa.y, ay0);
        if (__any(part1 > m1 + 8.f)) {
            float nm = fmaxf(m1, part1);
            float sc = __expf(m1 - nm);
            d1 *= sc; ax1 *= sc; ay1 *= sc; m1 = nm;
        }
        float pe1 = __expf(part1 - m1);
        d1 += pe1;
        ax1 = fmaf(pe1, xb.x, ax1);
        ay1 = fmaf(pe1, xb.y, ay1);
    }
    if (p < re) {
        int2 e0 = csr[p];
        float2 xa = *(const float2*)(xl + (size_t)e0.x * 128 + c0);
        float ea0 = __int_as_float(e0.y);
        float mx0 = xa.x + fmaf(ea0, we2.x, xr2.x);
        float my0 = xa.y + fmaf(ea0, we2.y, xr2.y);
        mx0 = fmaxf(mx0, NEG_SLOPE * mx0);
        my0 = fmaxf(my0, NEG_SLOPE * my0);
        float part0 = head16_sum(mx0 * at2.x + my0 * at2.y);
        if (__any(part0 > m0 + 8.f)) {
            float nm = fmaxf(m0, part0);
            float sc = __expf(m0 - nm);
            d0 *= sc; ax0 *= sc; ay0 *= sc; m0 = nm;
        }
        float pe0 = __expf(part0 - m0);
        d0 += pe0;
        ax0 = fmaf(pe0, xa.x, ax0);
        ay0 = fmaf(pe0, xa.y, ay0);
    }
    // merge the two online states (exact)
    float mm = fmaxf(m0, m1);
    float s0 = __expf(m0 - mm), s1 = __expf(m1 - mm);
    float den = d0 * s0 + d1 * s1;
    float accx = ax0 * s0 + ax1 * s1;
    float accy = ay0 * s0 + ay1 * s1;
    float inv = 1.f / den;
    float2 bc2 = *(const float2*)(bc + c0);
    float ox = accx * inv + bc2.x;
    float oy = accy * inv + bc2.y;
    ox = ox > 0.f ? ox : (__expf(ox) - 1.f);  // elu
    oy = oy > 0.f ? oy : (__expf(oy) - 1.f);
    float2 h2 = *(const float2*)(h + (size_t)n * 128 + c0);
    float tx = h2.x + ox, ty = h2.y + oy;
    float sum = tx + ty;
#pragma unroll
    for (int m = 1; m < 64; m <<= 1) sum += __shfl_xor(sum, m);
    float mu = sum * (1.f / 128.f);
    float dx = tx - mu, dy = ty - mu;
    float vs = dx * dx + dy * dy;
#pragma unroll
    for (int m = 1; m < 64; m <<= 1) vs += __shfl_xor(vs, m);
    float rstd = rsqrtf(vs * (1.f / 128.f) + LN_EPS);
    float2 g2 = *(const float2*)(ln_g + c0);
    float2 b2 = *(const float2*)(ln_b + c0);
    float2 hn;
    hn.x = dx * rstd * g2.x + b2.x;
    hn.y = dy * rstd * g2.y + b2.y;
    *(float2*)(h + (size_t)n * 128 + c0) = hn;
    if (h_out) *(float2*)(h_out + (size_t)n * 128 + c0) = hn;
}

// ---------------------------------------------------------------- outputs
// node_emb GEMM: 64-row tile in LDS (broadcast reads), thread = 16 rows x 1 col.

__global__ __launch_bounds__(256) void nodeemb_kernel(
    const float* __restrict__ h, const float* __restrict__ Wn, const float* __restrict__ bn,
    float* __restrict__ node_emb, int N_) {
    __shared__ float hs[64 * 128];
    int t = threadIdx.x;
    int row0 = blockIdx.x * 64;
    {
        const float4* src = (const float4*)(h + (size_t)row0 * 128);
        float4* dst = (float4*)hs;
        int maxv = (N_ - row0) * 32;
#pragma unroll
        for (int i = 0; i < 8; ++i) {
            int o = i * 256 + t;
            int oc = o < maxv ? o : 0;
            dst[o] = src[oc];
        }
    }
    __syncthreads();
    int j = t & 63;
    int rbase = (t >> 6) * 16;
    float acc[16];
    float bj = bn[j];
#pragma unroll
    for (int r = 0; r < 16; ++r) acc[r] = bj;
    for (int k = 0; k < 128; k += 4) {
        float w0 = Wn[k * 64 + j];
        float w1 = Wn[(k + 1) * 64 + j];
        float w2 = Wn[(k + 2) * 64 + j];
        float w3 = Wn[(k + 3) * 64 + j];
#pragma unroll
        for (int r = 0; r < 16; ++r) {
            float4 hv = *(const float4*)(&hs[(rbase + r) * 128 + k]);
            acc[r] = fmaf(hv.x, w0, acc[r]);
            acc[r] = fmaf(hv.y, w1, acc[r]);
            acc[r] = fmaf(hv.z, w2, acc[r]);
            acc[r] = fmaf(hv.w, w3, acc[r]);
        }
    }
#pragma unroll
    for (int r = 0; r < 16; ++r) {
        int row = row0 + rbase + r;
        if (row < N_) node_emb[(size_t)row * 64 + j] = acc[r];
    }
}

// batch segment-sum: wave = contiguous node chunk, register accumulate, ~1 flush/wave.
__global__ __launch_bounds__(256) void batch_kernel(
    const float* __restrict__ h, const int* __restrict__ batch,
    float* __restrict__ gsum, float* __restrict__ gcnt, int N_, int chunk) {
    int wave_id = (blockIdx.x * 256 + threadIdx.x) >> 6;
    int lane = threadIdx.x & 63;
    int w0 = wave_id * chunk;
    if (w0 >= N_) return;
    int w1 = w0 + chunk; if (w1 > N_) w1 = N_;
    int c0 = lane * 2;
    int cur_b = batch[w0];
    float accx = 0.f, accy = 0.f, cntf = 0.f;
    for (int n = w0; n < w1; ++n) {
        float2 h2 = *(const float2*)(h + (size_t)n * 128 + c0);
        int b = batch[n];
        if (b != cur_b) {
            atomicAdd(&gsum[cur_b * 128 + c0], accx);
            atomicAdd(&gsum[cur_b * 128 + c0 + 1], accy);
            if (lane == 0) atomicAdd(gcnt + cur_b, cntf);
            accx = accy = cntf = 0.f;
            cur_b = b;
        }
        accx += h2.x; accy += h2.y; cntf += 1.f;
    }
    atomicAdd(&gsum[cur_b * 128 + c0], accx);
    atomicAdd(&gsum[cur_b * 128 + c0 + 1], accy);
    if (lane == 0) atomicAdd(gcnt + cur_b, cntf);
}

__global__ void graph_kernel(const float* __restrict__ gsum, const float* __restrict__ gcnt,
                             const float* __restrict__ Wg1, const float* __restrict__ bg1,
                             const float* __restrict__ Wg2, const float* __restrict__ bg2,
                             float* __restrict__ graph_emb) {
    __shared__ float gm[8 * 128];
    __shared__ float t1[8 * 128];
    int t = threadIdx.x;
    for (int i = t; i < 1024; i += 256) {
        int b = i >> 7;
        float c = gcnt[b];
        c = c > 1.f ? c : 1.f;
        gm[i] = gsum[i] / c;
    }
    __syncthreads();
    for (int i = t; i < 1024; i += 256) {
        int r = i >> 7, j = i & 127;
        float acc = bg1[j];
        for (int k = 0; k < 128; ++k) acc += gm[r * 128 + k] * Wg1[k * 128 + j];
        t1[i] = acc > 0.f ? acc : (__expf(acc) - 1.f);
    }
    __syncthreads();
    for (int i = t; i < 512; i += 256) {
        int r = i >> 6, j = i & 63;
        float acc = bg2[j];
        for (int k = 0; k < 128; ++k) acc += t1[r * 128 + k] * Wg2[k * 64 + j];
        graph_emb[r * 64 + j] = acc;
    }
}

// ---------------------------------------------------------------- launch

extern "C" void kernel_launch(void* const* d_in, const int* in_sizes, int n_in,
                              void* d_out, int out_size, void* d_ws, size_t ws_size,
                              hipStream_t stream) {
    const float* x         = (const float*)d_in[0];
    const int*   edge_index= (const int*)d_in[1];
    const float* edge_attr = (const float*)d_in[2];
    const int*   batch     = (const int*)d_in[3];
    const float* W_in      = (const float*)d_in[4];
    const float* b_in      = (const float*)d_in[5];
    const float* Wl        = (const float*)d_in[6];
    const float* bl        = (const float*)d_in[7];
    const float* Wr        = (const float*)d_in[8];
    const float* br        = (const float*)d_in[9];
    const float* We        = (const float*)d_in[10];
    const float* att       = (const float*)d_in[11];
    const float* bc        = (const float*)d_in[12];
    const float* ln_g      = (const float*)d_in[13];
    const float* ln_b      = (const float*)d_in[14];
    const float* Wn        = (const float*)d_in[15];
    const float* bn        = (const float*)d_in[16];
    const float* Wg1       = (const float*)d_in[17];
    const float* bg1       = (const float*)d_in[18];
    const float* Wg2       = (const float*)d_in[19];
    const float* bg2       = (const float*)d_in[20];

    const int N_ = in_sizes[3];   // batch is (N,)
    const int E_ = in_sizes[2];   // edge_attr is (E,1)

    const int* src0 = edge_index;
    const int* dst0 = edge_index + E_;

    float* ws = (float*)d_ws;
    float* h      = ws;                              // N*128
    float* xl     = h + (size_t)N_ * 128;            // N*128
    float* xr     = xl + (size_t)N_ * 128;           // N*128
    float* Wt     = xr + (size_t)N_ * 128;           // 6*16384
    float* gsum   = Wt + 6 * 16384;                  // 1024
    float* gcnt   = gsum + 1024;                     // 16 (8 used)
    float* easum  = gcnt + 16;                       // N
    int* cnt      = (int*)(easum + N_);              // N
    int* rowstart = cnt + N_;                        // N+2 (pad for int2 align)
    int* cursor   = rowstart + N_ + 2;               // N
    int2* csr     = (int2*)(cursor + N_);            // E+N (8B aligned)

    float* out_f     = (float*)d_out;
    float* node_emb  = out_f;                               // N*64
    float* graph_emb = out_f + (size_t)N_ * 64;             // 8*64
    float* h_out     = out_f + (size_t)N_ * 64 + 8 * 64;    // N*128

    // gsum, gcnt, easum, cnt are contiguous -> one memset
    hipMemsetAsync(gsum, 0, (1024 + 16 + 2 * (size_t)N_) * sizeof(float), stream);

    wtrans_kernel<<<(6 * 16384 + 255) / 256, 256, 0, stream>>>(Wl, Wr, Wt);
    count_kernel<<<(E_ + 255) / 256, 256, 0, stream>>>(dst0, edge_attr, cnt, easum, E_);
    scan_kernel<<<1, 1024, 0, stream>>>(cnt, rowstart, N_);
    selfloop_kernel<<<(N_ + 255) / 256, 256, 0, stream>>>(cnt, easum, rowstart, cursor,
                                                          csr, N_);
    scatter_kernel<<<(E_ + 255) / 256, 256, 0, stream>>>(src0, dst0, edge_attr, cursor,
                                                         csr, E_);
    in_proj_kernel<<<((N_ * 128) + 255) / 256, 256, 0, stream>>>(x, W_in, b_in, h, N_);

    for (int l = 0; l < 3; ++l) {
        proj_kernel<<<(N_ + 31) / 32, 256, 0, stream>>>(
            h, Wt + l * 16384, Wt + (3 + l) * 16384, bl + l * 128, br + l * 128, xl, xr, N_);
        aggregate_kernel<<<(N_ + 3) / 4, 256, 0, stream>>>(
            h, xl, xr, rowstart, csr, We + l * 128, att + l * 128,
            bc + l * 128, ln_g + l * 128, ln_b + l * 128,
            (l == 2) ? h_out : (float*)nullptr, N_);
    }

    nodeemb_kernel<<<(N_ + 63) / 64, 256, 0, stream>>>(h, Wn, bn, node_emb, N_);
    {
        int total_waves = 2048;
        int chunk = (N_ + total_waves - 1) / total_waves;
        batch_kernel<<<total_waves / 4, 256, 0, stream>>>(h, batch, gsum, gcnt, N_, chunk);
    }
    graph_kernel<<<1, 256, 0, stream>>>(gsum, gcnt, Wg1, bg1, Wg2, bg2, graph_emb);
}

// Round 6
// 673.281 us; speedup vs baseline: 4.8369x; 1.3662x over previous
//
#include <hip/hip_runtime.h>

#define NEG_SLOPE 0.2f
#define LN_EPS 1e-5f

typedef __attribute__((ext_vector_type(8))) short bf16x8;
typedef __attribute__((ext_vector_type(4))) float f32x4;

__device__ __forceinline__ ushort f2bf(float f) {  // round-to-nearest-even
    uint u = __float_as_uint(f);
    u += 0x7fffu + ((u >> 16) & 1u);
    return (ushort)(u >> 16);
}

// ---------------------------------------------------------------- prep kernels

__global__ void count_kernel(const int* __restrict__ dst0, const float* __restrict__ eattr,
                             int* __restrict__ cnt, float* __restrict__ easum, int E_) {
    int e = blockIdx.x * 256 + threadIdx.x;
    if (e >= E_) return;
    int d = dst0[e];
    atomicAdd(&cnt[d], 1);
    atomicAdd(&easum[d], eattr[e]);
}

__global__ void scan_kernel(const int* __restrict__ cnt, int* __restrict__ rowstart, int N_) {
    __shared__ int lds[1024];
    int t = threadIdx.x;
    int chunk = (N_ + 1023) >> 10;
    int begin = t * chunk;
    int end = begin + chunk; if (end > N_) end = N_; if (begin > N_) begin = N_;
    int s = 0;
    for (int i = begin; i < end; ++i) s += cnt[i] + 1;
    lds[t] = s;
    __syncthreads();
    for (int off = 1; off < 1024; off <<= 1) {
        int v = (t >= off) ? lds[t - off] : 0;
        __syncthreads();
        lds[t] += v;
        __syncthreads();
    }
    int run = lds[t] - s;  // exclusive base
    for (int i = begin; i < end; ++i) { rowstart[i] = run; run += cnt[i] + 1; }
    if (t == 1023) rowstart[N_] = lds[1023];
}

__global__ void selfloop_kernel(const int* __restrict__ cnt, const float* __restrict__ easum,
                                const int* __restrict__ rowstart, int* __restrict__ cursor,
                                int2* __restrict__ csr, int N_) {
    int n = blockIdx.x * 256 + threadIdx.x;
    if (n >= N_) return;
    int rs = rowstart[n];
    int c = cnt[n];
    float ea = easum[n] / (float)(c > 1 ? c : 1);
    csr[rs] = make_int2(n, __float_as_int(ea));
    cursor[n] = rs + 1;
}

__global__ void scatter_kernel(const int* __restrict__ src0, const int* __restrict__ dst0,
                               const float* __restrict__ eattr, int* __restrict__ cursor,
                               int2* __restrict__ csr, int E_) {
    int e = blockIdx.x * 256 + threadIdx.x;
    if (e >= E_) return;
    int d = dst0[e];
    int p = atomicAdd(&cursor[d], 1);
    csr[p] = make_int2(src0[e], __float_as_int(eattr[e]));
}

// pack weights into bf16 MFMA B-fragment order.
// region [0,98304): Wl0,Wl1,Wl2,Wr0,Wr1,Wr2 (128x128);
// [98304,102400): W_in (32x128); [102400,110592): Wn (128x64).
// rel = ((ks*nc16 + c)*64 + lane)*8 + j ; k = ks*32+(lane>>4)*8+j ; col = c*16+(lane&15)
__global__ void pack_kernel(const float* __restrict__ Wl, const float* __restrict__ Wr,
                            const float* __restrict__ Win, const float* __restrict__ Wn,
                            ushort* __restrict__ out) {
    int idx = blockIdx.x * 256 + threadIdx.x;
    if (idx >= 110592) return;
    const float* src; int Ncol, rel;
    if (idx < 98304) {
        int m = idx >> 14; rel = idx & 16383;
        src = m < 3 ? Wl + m * 16384 : Wr + (m - 3) * 16384;
        Ncol = 128;
    } else if (idx < 102400) {
        rel = idx - 98304; src = Win; Ncol = 128;
    } else {
        rel = idx - 102400; src = Wn; Ncol = 64;
    }
    int j = rel & 7, lane = (rel >> 3) & 63, rest = rel >> 9;
    int nc16 = Ncol >> 4;
    int c = rest % nc16, ks = rest / nc16;
    int k = ks * 32 + ((lane >> 4) << 3) + j;
    int col = c * 16 + (lane & 15);
    out[idx] = f2bf(src[k * Ncol + col]);
}

__global__ void cvt_x_kernel(const float* __restrict__ x, ushort* __restrict__ xb, int total4) {
    int i = blockIdx.x * 256 + threadIdx.x;
    if (i >= total4) return;
    float4 v = *(const float4*)(x + i * 4);
    ushort4 o;
    o.x = f2bf(v.x); o.y = f2bf(v.y); o.z = f2bf(v.z); o.w = f2bf(v.w);
    *(ushort4*)(xb + i * 4) = o;
}

// ---------------------------------------------------------------- MFMA GEMMs
// A-frag: row = lane&15, k = (lane>>4)*8 + j (16B contiguous per lane).
// D-frag: col = lane&15, row = (lane>>4)*4 + reg.

// in-proj: x_bf (N x 32) @ W_in -> h (f32) and h_bf. one K-step.
__global__ __launch_bounds__(256) void mfma_inproj(
    const ushort* __restrict__ x_bf, const ushort* __restrict__ Wp,
    const float* __restrict__ b_in, float* __restrict__ h, ushort* __restrict__ h_bf, int N_) {
    int wave = threadIdx.x >> 6, lane = threadIdx.x & 63;
    int row0 = blockIdx.x * 64 + wave * 16;
    int arow = row0 + (lane & 15); if (arow >= N_) arow = N_ - 1;
    int koff = (lane >> 4) * 8;
    bf16x8 a = *(const bf16x8*)(x_bf + (size_t)arow * 32 + koff);
    f32x4 acc[8];
#pragma unroll
    for (int c = 0; c < 8; ++c) acc[c] = {0.f, 0.f, 0.f, 0.f};
#pragma unroll
    for (int c = 0; c < 8; ++c) {
        bf16x8 b = *(const bf16x8*)(Wp + ((size_t)c * 64 + lane) * 8);
        acc[c] = __builtin_amdgcn_mfma_f32_16x16x32_bf16(a, b, acc[c], 0, 0, 0);
    }
    int srow = row0 + (lane >> 4) * 4;
    int scol = lane & 15;
#pragma unroll
    for (int c = 0; c < 8; ++c) {
        float bi = b_in[c * 16 + scol];
#pragma unroll
        for (int r = 0; r < 4; ++r) {
            int row = srow + r;
            if (row < N_) {
                float v = acc[c][r] + bi;
                h[(size_t)row * 128 + c * 16 + scol] = v;
                h_bf[(size_t)row * 128 + c * 16 + scol] = f2bf(v);
            }
        }
    }
}

// layer proj: h_bf (N x 128) @ Wl, Wr -> xl_bf, xr_bf (bf16)
__global__ __launch_bounds__(256) void mfma_proj(
    const ushort* __restrict__ h_bf, const ushort* __restrict__ Wlp,
    const ushort* __restrict__ Wrp, const float* __restrict__ bl, const float* __restrict__ br,
    ushort* __restrict__ xl, ushort* __restrict__ xr, int N_) {
    int wave = threadIdx.x >> 6, lane = threadIdx.x & 63;
    int row0 = blockIdx.x * 64 + wave * 16;
    int arow = row0 + (lane & 15); if (arow >= N_) arow = N_ - 1;
    int koff = (lane >> 4) * 8;
    f32x4 accL[8], accR[8];
#pragma unroll
    for (int c = 0; c < 8; ++c) { accL[c] = {0.f, 0.f, 0.f, 0.f}; accR[c] = {0.f, 0.f, 0.f, 0.f}; }
#pragma unroll
    for (int ks = 0; ks < 4; ++ks) {
        bf16x8 a = *(const bf16x8*)(h_bf + (size_t)arow * 128 + ks * 32 + koff);
        const ushort* wl = Wlp + ((size_t)ks * 8 * 64 + lane) * 8;
        const ushort* wr = Wrp + ((size_t)ks * 8 * 64 + lane) * 8;
#pragma unroll
        for (int c = 0; c < 8; ++c) {
            bf16x8 bL = *(const bf16x8*)(wl + c * 512);
            accL[c] = __builtin_amdgcn_mfma_f32_16x16x32_bf16(a, bL, accL[c], 0, 0, 0);
            bf16x8 bR = *(const bf16x8*)(wr + c * 512);
            accR[c] = __builtin_amdgcn_mfma_f32_16x16x32_bf16(a, bR, accR[c], 0, 0, 0);
        }
    }
    int srow = row0 + (lane >> 4) * 4;
    int scol = lane & 15;
#pragma unroll
    for (int c = 0; c < 8; ++c) {
        float bLv = bl[c * 16 + scol];
        float bRv = br[c * 16 + scol];
#pragma unroll
        for (int r = 0; r < 4; ++r) {
            int row = srow + r;
            if (row < N_) {
                xl[(size_t)row * 128 + c * 16 + scol] = f2bf(accL[c][r] + bLv);
                xr[(size_t)row * 128 + c * 16 + scol] = f2bf(accR[c][r] + bRv);
            }
        }
    }
}

// node_emb: h_bf (N x 128) @ Wn (128 x 64) + bn
__global__ __launch_bounds__(256) void mfma_nodeemb(
    const ushort* __restrict__ h_bf, const ushort* __restrict__ Wp,
    const float* __restrict__ bn, float* __restrict__ node_emb, int N_) {
    int wave = threadIdx.x >> 6, lane = threadIdx.x & 63;
    int row0 = blockIdx.x * 64 + wave * 16;
    int arow = row0 + (lane & 15); if (arow >= N_) arow = N_ - 1;
    int koff = (lane >> 4) * 8;
    f32x4 acc[4];
#pragma unroll
    for (int c = 0; c < 4; ++c) acc[c] = {0.f, 0.f, 0.f, 0.f};
#pragma unroll
    for (int ks = 0; ks < 4; ++ks) {
        bf16x8 a = *(const bf16x8*)(h_bf + (size_t)arow * 128 + ks * 32 + koff);
#pragma unroll
        for (int c = 0; c < 4; ++c) {
            bf16x8 b = *(const bf16x8*)(Wp + ((size_t)(ks * 4 + c) * 64 + lane) * 8);
            acc[c] = __builtin_amdgcn_mfma_f32_16x16x32_bf16(a, b, acc[c], 0, 0, 0);
        }
    }
    int srow = row0 + (lane >> 4) * 4;
    int scol = lane & 15;
#pragma unroll
    for (int c = 0; c < 4; ++c) {
        float bi = bn[c * 16 + scol];
#pragma unroll
        for (int r = 0; r < 4; ++r) {
            int row = srow + r;
            if (row < N_) node_emb[(size_t)row * 64 + c * 16 + scol] = acc[c][r] + bi;
        }
    }
}

// ---------------------------------------------------------------- per-node aggregation
// DPP 16-lane head reduce (full-rate VALU).

__device__ __forceinline__ float head16_sum(float x) {
    int v;
    v = __builtin_amdgcn_update_dpp(0, __float_as_int(x), 0xB1, 0xF, 0xF, true);
    x += __int_as_float(v);
    v = __builtin_amdgcn_update_dpp(0, __float_as_int(x), 0x4E, 0xF, 0xF, true);
    x += __int_as_float(v);
    v = __builtin_amdgcn_update_dpp(0, __float_as_int(x), 0x141, 0xF, 0xF, true);
    x += __int_as_float(v);
    v = __builtin_amdgcn_update_dpp(0, __float_as_int(x), 0x140, 0xF, 0xF, true);
    x += __int_as_float(v);
    return x;
}

// one wave per node; lane = 2 channels; defer-max online softmax; two
// independent edge states for ILP. xl/xr gathers are bf16 (half traffic).

__global__ __launch_bounds__(256) void aggregate_kernel(
    float* __restrict__ h, const ushort* __restrict__ xl, const ushort* __restrict__ xr,
    const int* __restrict__ rowstart, const int2* __restrict__ csr,
    const float* __restrict__ We, const float* __restrict__ att, const float* __restrict__ bc,
    const float* __restrict__ ln_g, const float* __restrict__ ln_b,
    ushort* __restrict__ h_bf, float* __restrict__ h_out, int N_) {
    int wave = threadIdx.x >> 6, lane = threadIdx.x & 63;
    int n = blockIdx.x * 4 + wave;
    if (n >= N_) return;
    int c0 = lane * 2;
    int head = lane >> 4;
    uint vr = *(const uint*)(xr + (size_t)n * 128 + c0);
    float xr2x = __uint_as_float(vr << 16);
    float xr2y = __uint_as_float(vr & 0xffff0000u);
    float2 we2 = *(const float2*)(We + c0);
    float2 at2 = *(const float2*)(att + head * 32 + (c0 & 31));
    int rs = rowstart[n], re = rowstart[n + 1];
    float m0 = -3.0e38f, d0 = 0.f, ax0 = 0.f, ay0 = 0.f;
    float m1 = -3.0e38f, d1 = 0.f, ax1 = 0.f, ay1 = 0.f;
    int p = rs;
    for (; p + 2 <= re; p += 2) {
        int2 e0 = csr[p];
        int2 e1 = csr[p + 1];
        uint va = *(const uint*)(xl + (size_t)e0.x * 128 + c0);
        uint vb = *(const uint*)(xl + (size_t)e1.x * 128 + c0);
        float xax = __uint_as_float(va << 16), xay = __uint_as_float(va & 0xffff0000u);
        float xbx = __uint_as_float(vb << 16), xby = __uint_as_float(vb & 0xffff0000u);
        float ea0 = __int_as_float(e0.y), ea1 = __int_as_float(e1.y);
        float mx0 = xax + fmaf(ea0, we2.x, xr2x);
        float my0 = xay + fmaf(ea0, we2.y, xr2y);
        mx0 = fmaxf(mx0, NEG_SLOPE * mx0);
        my0 = fmaxf(my0, NEG_SLOPE * my0);
        float part0 = head16_sum(mx0 * at2.x + my0 * at2.y);
        float mx1 = xbx + fmaf(ea1, we2.x, xr2x);
        float my1 = xby + fmaf(ea1, we2.y, xr2y);
        mx1 = fmaxf(mx1, NEG_SLOPE * mx1);
        my1 = fmaxf(my1, NEG_SLOPE * my1);
        float part1 = head16_sum(mx1 * at2.x + my1 * at2.y);
        if (__any(part0 > m0 + 8.f)) {
            float nm = fmaxf(m0, part0);
            float sc = __expf(m0 - nm);
            d0 *= sc; ax0 *= sc; ay0 *= sc; m0 = nm;
        }
        float pe0 = __expf(part0 - m0);
        d0 += pe0;
        ax0 = fmaf(pe0, xax, ax0);
        ay0 = fmaf(pe0, xay, ay0);
        if (__any(part1 > m1 + 8.f)) {
            float nm = fmaxf(m1, part1);
            float sc = __expf(m1 - nm);
            d1 *= sc; ax1 *= sc; ay1 *= sc; m1 = nm;
        }
        float pe1 = __expf(part1 - m1);
        d1 += pe1;
        ax1 = fmaf(pe1, xbx, ax1);
        ay1 = fmaf(pe1, xby, ay1);
    }
    if (p < re) {
        int2 e0 = csr[p];
        uint va = *(const uint*)(xl + (size_t)e0.x * 128 + c0);
        float xax = __uint_as_float(va << 16), xay = __uint_as_float(va & 0xffff0000u);
        float ea0 = __int_as_float(e0.y);
        float mx0 = xax + fmaf(ea0, we2.x, xr2x);
        float my0 = xay + fmaf(ea0, we2.y, xr2y);
        mx0 = fmaxf(mx0, NEG_SLOPE * mx0);
        my0 = fmaxf(my0, NEG_SLOPE * my0);
        float part0 = head16_sum(mx0 * at2.x + my0 * at2.y);
        if (__any(part0 > m0 + 8.f)) {
            float nm = fmaxf(m0, part0);
            float sc = __expf(m0 - nm);
            d0 *= sc; ax0 *= sc; ay0 *= sc; m0 = nm;
        }
        float pe0 = __expf(part0 - m0);
        d0 += pe0;
        ax0 = fmaf(pe0, xax, ax0);
        ay0 = fmaf(pe0, xay, ay0);
    }
    float mm = fmaxf(m0, m1);
    float s0 = __expf(m0 - mm), s1 = __expf(m1 - mm);
    float den = d0 * s0 + d1 * s1;
    float accx = ax0 * s0 + ax1 * s1;
    float accy = ay0 * s0 + ay1 * s1;
    float inv = 1.f / den;
    float2 bc2 = *(const float2*)(bc + c0);
    float ox = accx * inv + bc2.x;
    float oy = accy * inv + bc2.y;
    ox = ox > 0.f ? ox : (__expf(ox) - 1.f);  // elu
    oy = oy > 0.f ? oy : (__expf(oy) - 1.f);
    float2 h2 = *(const float2*)(h + (size_t)n * 128 + c0);
    float tx = h2.x + ox, ty = h2.y + oy;
    float sum = tx + ty;
#pragma unroll
    for (int m = 1; m < 64; m <<= 1) sum += __shfl_xor(sum, m);
    float mu = sum * (1.f / 128.f);
    float dx = tx - mu, dy = ty - mu;
    float vs = dx * dx + dy * dy;
#pragma unroll
    for (int m = 1; m < 64; m <<= 1) vs += __shfl_xor(vs, m);
    float rstd = rsqrtf(vs * (1.f / 128.f) + LN_EPS);
    float2 g2 = *(const float2*)(ln_g + c0);
    float2 b2 = *(const float2*)(ln_b + c0);
    float2 hn;
    hn.x = dx * rstd * g2.x + b2.x;
    hn.y = dy * rstd * g2.y + b2.y;
    *(float2*)(h + (size_t)n * 128 + c0) = hn;
    uint packed = (uint)f2bf(hn.x) | ((uint)f2bf(hn.y) << 16);
    *(uint*)(h_bf + (size_t)n * 128 + c0) = packed;
    if (h_out) *(float2*)(h_out + (size_t)n * 128 + c0) = hn;
}

// ---------------------------------------------------------------- outputs

// batch segment-sum: wave = contiguous node chunk, register accumulate, ~1 flush/wave.
__global__ __launch_bounds__(256) void batch_kernel(
    const float* __restrict__ h, const int* __restrict__ batch,
    float* __restrict__ gsum, float* __restrict__ gcnt, int N_, int chunk) {
    int wave_id = (blockIdx.x * 256 + threadIdx.x) >> 6;
    int lane = threadIdx.x & 63;
    int w0 = wave_id * chunk;
    if (w0 >= N_) return;
    int w1 = w0 + chunk; if (w1 > N_) w1 = N_;
    int c0 = lane * 2;
    int cur_b = batch[w0];
    float accx = 0.f, accy = 0.f, cntf = 0.f;
    for (int n = w0; n < w1; ++n) {
        float2 h2 = *(const float2*)(h + (size_t)n * 128 + c0);
        int b = batch[n];
        if (b != cur_b) {
            atomicAdd(&gsum[cur_b * 128 + c0], accx);
            atomicAdd(&gsum[cur_b * 128 + c0 + 1], accy);
            if (lane == 0) atomicAdd(gcnt + cur_b, cntf);
            accx = accy = cntf = 0.f;
            cur_b = b;
        }
        accx += h2.x; accy += h2.y; cntf += 1.f;
    }
    atomicAdd(&gsum[cur_b * 128 + c0], accx);
    atomicAdd(&gsum[cur_b * 128 + c0 + 1], accy);
    if (lane == 0) atomicAdd(gcnt + cur_b, cntf);
}

__global__ void graph_kernel(const float* __restrict__ gsum, const float* __restrict__ gcnt,
                             const float* __restrict__ Wg1, const float* __restrict__ bg1,
                             const float* __restrict__ Wg2, const float* __restrict__ bg2,
                             float* __restrict__ graph_emb) {
    __shared__ float gm[8 * 128];
    __shared__ float t1[8 * 128];
    int t = threadIdx.x;
    for (int i = t; i < 1024; i += 256) {
        int b = i >> 7;
        float c = gcnt[b];
        c = c > 1.f ? c : 1.f;
        gm[i] = gsum[i] / c;
    }
    __syncthreads();
    for (int i = t; i < 1024; i += 256) {
        int r = i >> 7, j = i & 127;
        float acc = bg1[j];
        for (int k = 0; k < 128; ++k) acc += gm[r * 128 + k] * Wg1[k * 128 + j];
        t1[i] = acc > 0.f ? acc : (__expf(acc) - 1.f);
    }
    __syncthreads();
    for (int i = t; i < 512; i += 256) {
        int r = i >> 6, j = i & 63;
        float acc = bg2[j];
        for (int k = 0; k < 128; ++k) acc += t1[r * 128 + k] * Wg2[k * 64 + j];
        graph_emb[r * 64 + j] = acc;
    }
}

// ---------------------------------------------------------------- launch

extern "C" void kernel_launch(void* const* d_in, const int* in_sizes, int n_in,
                              void* d_out, int out_size, void* d_ws, size_t ws_size,
                              hipStream_t stream) {
    const float* x         = (const float*)d_in[0];
    const int*   edge_index= (const int*)d_in[1];
    const float* edge_attr = (const float*)d_in[2];
    const int*   batch     = (const int*)d_in[3];
    const float* W_in      = (const float*)d_in[4];
    const float* b_in      = (const float*)d_in[5];
    const float* Wl        = (const float*)d_in[6];
    const float* bl        = (const float*)d_in[7];
    const float* Wr        = (const float*)d_in[8];
    const float* br        = (const float*)d_in[9];
    const float* We        = (const float*)d_in[10];
    const float* att       = (const float*)d_in[11];
    const float* bc        = (const float*)d_in[12];
    const float* ln_g      = (const float*)d_in[13];
    const float* ln_b      = (const float*)d_in[14];
    const float* Wn        = (const float*)d_in[15];
    const float* bn        = (const float*)d_in[16];
    const float* Wg1       = (const float*)d_in[17];
    const float* bg1       = (const float*)d_in[18];
    const float* Wg2       = (const float*)d_in[19];
    const float* bg2       = (const float*)d_in[20];

    const int N_ = in_sizes[3];   // batch is (N,)
    const int E_ = in_sizes[2];   // edge_attr is (E,1)

    const int* src0 = edge_index;
    const int* dst0 = edge_index + E_;

    float* ws = (float*)d_ws;
    float* h      = ws;                              // N*128 f32
    float* gsum   = h + (size_t)N_ * 128;            // 1024
    float* gcnt   = gsum + 1024;                     // 16 (8 used)
    float* easum  = gcnt + 16;                       // N
    int* cnt      = (int*)(easum + N_);              // N
    int* rowstart = cnt + N_;                        // N+2 (pad for int2 align)
    int* cursor   = rowstart + N_ + 2;               // N
    int2* csr     = (int2*)(cursor + N_);            // E+N (8B aligned)
    ushort* h_bf  = (ushort*)(csr + (size_t)(E_ + N_));   // N*128
    ushort* x_bf  = h_bf + (size_t)N_ * 128;              // N*32
    ushort* xl_bf = x_bf + (size_t)N_ * 32;               // N*128
    ushort* xr_bf = xl_bf + (size_t)N_ * 128;             // N*128
    ushort* wpack = xr_bf + (size_t)N_ * 128;             // 110592

    float* out_f     = (float*)d_out;
    float* node_emb  = out_f;                               // N*64
    float* graph_emb = out_f + (size_t)N_ * 64;             // 8*64
    float* h_out     = out_f + (size_t)N_ * 64 + 8 * 64;    // N*128

    // gsum, gcnt, easum, cnt contiguous -> one memset
    hipMemsetAsync(gsum, 0, (1024 + 16 + 2 * (size_t)N_) * sizeof(float), stream);

    pack_kernel<<<(110592 + 255) / 256, 256, 0, stream>>>(Wl, Wr, W_in, Wn, wpack);
    cvt_x_kernel<<<((N_ * 8) + 255) / 256, 256, 0, stream>>>(x, x_bf, N_ * 8);
    count_kernel<<<(E_ + 255) / 256, 256, 0, stream>>>(dst0, edge_attr, cnt, easum, E_);
    scan_kernel<<<1, 1024, 0, stream>>>(cnt, rowstart, N_);
    selfloop_kernel<<<(N_ + 255) / 256, 256, 0, stream>>>(cnt, easum, rowstart, cursor,
                                                          csr, N_);
    scatter_kernel<<<(E_ + 255) / 256, 256, 0, stream>>>(src0, dst0, edge_attr, cursor,
                                                         csr, E_);

    int gemm_blocks = (N_ + 63) / 64;
    mfma_inproj<<<gemm_blocks, 256, 0, stream>>>(x_bf, wpack + 98304, b_in, h, h_bf, N_);

    for (int l = 0; l < 3; ++l) {
        mfma_proj<<<gemm_blocks, 256, 0, stream>>>(
            h_bf, wpack + l * 16384, wpack + (3 + l) * 16384,
            bl + l * 128, br + l * 128, xl_bf, xr_bf, N_);
        aggregate_kernel<<<(N_ + 3) / 4, 256, 0, stream>>>(
            h, xl_bf, xr_bf, rowstart, csr, We + l * 128, att + l * 128,
            bc + l * 128, ln_g + l * 128, ln_b + l * 128,
            h_bf, (l == 2) ? h_out : (float*)nullptr, N_);
    }

    mfma_nodeemb<<<gemm_blocks, 256, 0, stream>>>(h_bf, wpack + 102400, bn, node_emb, N_);
    {
        int total_waves = 2048;
        int chunk = (N_ + total_waves - 1) / total_waves;
        batch_kernel<<<total_waves / 4, 256, 0, stream>>>(h, batch, gsum, gcnt, N_, chunk);
    }
    graph_kernel<<<1, 256, 0, stream>>>(gsum, gcnt, Wg1, bg1, Wg2, bg2, graph_emb);
}